// Round 11
// baseline (392.121 us; speedup 1.0000x reference)
//
#include <hip/hip_runtime.h>
#include <hip/hip_bf16.h>

#define NN 3072
#define HH 8

typedef short short8 __attribute__((ext_vector_type(8)));
typedef float float4v __attribute__((ext_vector_type(4)));
typedef unsigned short ushort4v __attribute__((ext_vector_type(4)));

__device__ __forceinline__ float bf2f(unsigned short u) {
  union { unsigned u; float f; } v; v.u = ((unsigned)u) << 16; return v.f;
}
__device__ __forceinline__ unsigned short f2bf(float f) {
  union { float f; unsigned u; } v; v.f = f;
  unsigned r = v.u + 0x7fffu + ((v.u >> 16) & 1u);
  return (unsigned short)(r >> 16);
}
// flag==1 -> buffers are bf16; flag==0 -> fp32
__device__ __forceinline__ float ldin(const void* p, size_t i, int isbf) {
  return isbf ? bf2f(((const unsigned short*)p)[i]) : ((const float*)p)[i];
}

// ---- dtype detect: adj is exactly {0.0,1.0}; fp32 words have low16==0 always ----
__global__ __launch_bounds__(256) void k_detect(const unsigned* __restrict__ aw,
                                                int* __restrict__ flag) {
  __shared__ int s;
  if (threadIdx.x == 0) s = 0;
  __syncthreads();
  int any = 0;
  for (int i = threadIdx.x; i < 16384; i += 256)
    any |= ((aw[i] & 0xFFFFu) != 0u);
  if (any) s = 1;   // benign race
  __syncthreads();
  if (threadIdx.x == 0) *flag = s;
}

// ---- build AND-mask table in MFMA-A-fragment order:
//      chunk (tr16, jb32): lane(q,l) elem i = mask[row=tr*16+l][j=jb*32+q*8+i],
//      value 0xFFFF (keep bf16 bits) or 0x0000 ----
__global__ __launch_bounds__(256) void k_maskfrag(const void* __restrict__ adj,
                                                  const int* __restrict__ flag,
                                                  unsigned short* __restrict__ maskF) {
  int isbf = *flag;
  int w = threadIdx.x >> 6, lane = threadIdx.x & 63;
  int q = lane >> 4, l = lane & 15;
  int chunk = blockIdx.x * 4 + w;
  int jb = chunk % (NN / 32);
  int tr = chunk / (NN / 32);
  int row = tr * 16 + l;
  int jbase = jb * 32 + q * 8;
  short8 m;
  if (isbf) {
    short8 v = *(const short8*)((const unsigned short*)adj + (size_t)row * NN + jbase);
#pragma unroll
    for (int i = 0; i < 8; i++) m[i] = v[i] ? (short)0xFFFF : (short)0;
  } else {
    const float* ap = (const float*)adj + (size_t)row * NN + jbase;
    float4v v0 = *(const float4v*)ap;
    float4v v1 = *(const float4v*)(ap + 4);
#pragma unroll
    for (int i = 0; i < 8; i++)
      m[i] = ((i < 4 ? v0[i] : v1[i - 4]) != 0.f) ? (short)0xFFFF : (short)0;
  }
  *(short8*)(maskF + (size_t)chunk * 512 + lane * 8) = m;
}

// ---- mergeState: h = x + (obs==1) * theta ----
__global__ __launch_bounds__(256) void k_merge(const void* __restrict__ x,
                                               const int* __restrict__ obs,
                                               const void* __restrict__ theta,
                                               const int* __restrict__ flag,
                                               unsigned short* __restrict__ h) {
  int isbf = *flag;
  int i = blockIdx.x * 256 + threadIdx.x;
  int row = i >> 8, c = i & 255;
  float v = ldin(x, i, isbf);
  if (obs[row] == 1) v += ldin(theta, c, isbf);
  h[i] = f2bf(v);
}

// ---- batched 16x16 LDS transpose: in[b][R][C] -> out[b][C][R] (out bf16) ----
__global__ __launch_bounds__(256) void k_transpose(const void* __restrict__ in,
                                                   const int* __restrict__ flag,
                                                   unsigned short* __restrict__ out,
                                                   int R, int C) {
  __shared__ __align__(16) unsigned short tile[16][17];
  int isbf = *flag;
  int b = blockIdx.z;
  size_t base = (size_t)b * R * C;
  unsigned short* pout = out + base;
  int r0 = blockIdx.y * 16, c0 = blockIdx.x * 16;
  int tc = threadIdx.x & 15, tr = threadIdx.x >> 4;
  tile[tr][tc] = f2bf(ldin(in, base + (size_t)(r0 + tr) * C + (c0 + tc), isbf));
  __syncthreads();
  pout[(size_t)(c0 + tr) * R + (r0 + tc)] = tile[tc][tr];
}

// ---- fused GEMM: 32 rows x 128 cols per block; epilogue writes WhTf directly
//      in MFMA-B-fragment order via per-wave LDS transpose (no scatter, no repack) ----
template<int K>
__global__ __launch_bounds__(256) void k_gemm_fused(const unsigned short* __restrict__ A,
                                                    const unsigned short* __restrict__ WT,
                                                    unsigned short* __restrict__ WhTf,
                                                    long aOff, long wOff) {
  __shared__ __align__(16) unsigned short tile[4][2][32][17];
  int head = blockIdx.y;
  A += (size_t)head * aOff; WT += (size_t)head * wOff;
  int jb = blockIdx.x;                 // 32-row tile index (j-block for attn)
  int rowbase = jb * 32;
  int t = threadIdx.x;
  int w = t >> 6, lane = t & 63;
  int q = lane >> 4, l = lane & 15;
  int colbase = w * 32;
  float4v acc[2][2];
#pragma unroll
  for (int rt = 0; rt < 2; rt++)
#pragma unroll
    for (int ct = 0; ct < 2; ct++) { float4v z = {0.f, 0.f, 0.f, 0.f}; acc[rt][ct] = z; }

  for (int kb = 0; kb < K; kb += 32) {
    short8 af[2], bfr[2];
#pragma unroll
    for (int rt = 0; rt < 2; rt++)
      af[rt] = *(const short8*)(A + (size_t)(rowbase + rt * 16 + l) * K + kb + q * 8);
#pragma unroll
    for (int ct = 0; ct < 2; ct++)
      bfr[ct] = *(const short8*)(WT + (size_t)(colbase + ct * 16 + l) * K + kb + q * 8);
#pragma unroll
    for (int rt = 0; rt < 2; rt++)
#pragma unroll
      for (int ct = 0; ct < 2; ct++)
        acc[rt][ct] = __builtin_amdgcn_mfma_f32_16x16x32_bf16(af[rt], bfr[ct], acc[rt][ct], 0, 0, 0);
  }
  // C/D layout (row = rt*16 + q*4 + reg, col = l) -> LDS
#pragma unroll
  for (int rt = 0; rt < 2; rt++)
#pragma unroll
    for (int ct = 0; ct < 2; ct++)
#pragma unroll
      for (int reg = 0; reg < 4; reg++)
        tile[w][ct][rt * 16 + q * 4 + reg][l] = f2bf(acc[rt][ct][reg]);
  __syncthreads();
  // B-frag layout (lane(q,l) holds rows q*8+i of col l) -> coalesced 1KB store
#pragma unroll
  for (int ct = 0; ct < 2; ct++) {
    short8 r8;
#pragma unroll
    for (int i = 0; i < 8; i++) r8[i] = tile[w][ct][q * 8 + i][l];
    size_t chunk = ((size_t)head * (NN / 32) + jb) * 8 + (w * 2 + ct);
    *(short8*)(WhTf + chunk * 512 + lane * 8) = r8;
  }
}

// ---- out-layer GEMM, K split across blocks into fp32 partials ----
template<int K, int KS>
__global__ __launch_bounds__(256) void k_gemm_out(const unsigned short* __restrict__ A,
                                                  const unsigned short* __restrict__ WT,
                                                  float* __restrict__ gpart) {
  constexpr int KC = K / KS;
  int ks = blockIdx.y;
  int rowbase = blockIdx.x * 16;
  int t = threadIdx.x;
  int w = t >> 6, lane = t & 63;
  int q = lane >> 4, l = lane & 15;
  int colbase = w * 16;
  float4v acc = {0.f, 0.f, 0.f, 0.f};
  for (int kb = ks * KC; kb < ks * KC + KC; kb += 32) {
    short8 af = *(const short8*)(A + (size_t)(rowbase + l) * K + kb + q * 8);
    short8 bfr = *(const short8*)(WT + (size_t)(colbase + l) * K + kb + q * 8);
    acc = __builtin_amdgcn_mfma_f32_16x16x32_bf16(af, bfr, acc, 0, 0, 0);
  }
#pragma unroll
  for (int reg = 0; reg < 4; reg++) {
    int r = rowbase + q * 4 + reg;
    int n = colbase + l;
    gpart[((size_t)ks * 64 + n) * NN + r] = acc[reg];
  }
}

// ---- combine K-split partials, emit WhoTf in fragment order (DC=64) ----
template<int KS>
__global__ __launch_bounds__(256) void k_gemm_red(const float* __restrict__ gpart,
                                                  unsigned short* __restrict__ WhoTf) {
  int tid = blockIdx.x * 256 + threadIdx.x;   // over 64*NN
  int r = tid % NN, n = tid / NN;
  float s = 0.f;
#pragma unroll
  for (int ks = 0; ks < KS; ks++) s += gpart[((size_t)ks * 64 + n) * NN + r];
  int jb = r >> 5, q = (r >> 3) & 3, i = r & 7, ct = n >> 4, l = n & 15;
  WhoTf[((size_t)(jb * 4 + ct)) * 512 + (q * 16 + l) * 8 + i] = f2bf(s);
}

// ---- f1/f2 from fragment-order WhTf: coalesced loads + shuffle reduce ----
template<int DC>
__global__ __launch_bounds__(256) void k_f12f(const unsigned short* __restrict__ WhTf,
                                              const void* __restrict__ avec,
                                              const int* __restrict__ flag,
                                              float* __restrict__ f1, float* __restrict__ f2) {
  constexpr int NCT = DC / 16;
  int isbf = *flag;
  int head = blockIdx.y;
  int w = threadIdx.x >> 6, lane = threadIdx.x & 63;
  int q = lane >> 4, l = lane & 15;
  int jbIdx = blockIdx.x * 4 + w;
  size_t abase = (size_t)head * 2 * DC;
  float s1[8], s2[8];
#pragma unroll
  for (int i = 0; i < 8; i++) { s1[i] = 0.f; s2[i] = 0.f; }
#pragma unroll
  for (int ct = 0; ct < NCT; ct++) {
    short8 v = *(const short8*)(WhTf + (((size_t)head * (NN / 32) + jbIdx) * NCT + ct) * 512 + lane * 8);
    float a1v = ldin(avec, abase + ct * 16 + l, isbf);
    float a2v = ldin(avec, abase + DC + ct * 16 + l, isbf);
#pragma unroll
    for (int i = 0; i < 8; i++) {
      float f = bf2f((unsigned short)v[i]);
      s1[i] += f * a1v;
      s2[i] += f * a2v;
    }
  }
#pragma unroll
  for (int d = 1; d < 16; d <<= 1)
#pragma unroll
    for (int i = 0; i < 8; i++) {
      s1[i] += __shfl_xor(s1[i], d, 64);
      s2[i] += __shfl_xor(s2[i], d, 64);
    }
  if (l == 0) {
    int r = jbIdx * 32 + q * 8;
#pragma unroll
    for (int i = 0; i < 8; i++) {
      f1[head * NN + r + i] = s1[i];
      f2[head * NN + r + i] = s2[i];
    }
  }
}

// ---- attention partial: barrier-free, LDS-free; full-DCOL waves, AND-mask
//      table (no per-elem cndmask), ones-MFMA denominator, bf16 frag-order
//      partials, head pinned to XCD via blockIdx.x % NH ----
template<int DCOL, int S>
__global__ __launch_bounds__(256, 4) void k_attn_part(
    const unsigned short* __restrict__ maskF,
    const float* __restrict__ f1g, const float* __restrict__ f2g,
    const unsigned short* __restrict__ WhTf,
    unsigned short* __restrict__ pnum, float* __restrict__ pden, int NH) {
  constexpr int NCT = DCOL / 16;
  constexpr int JCH = NN / S;
  int blk = blockIdx.x;
  int head = blk % NH;               // lowest bits -> XCD pin for NH=8
  int rest = blk / NH;
  int js = rest % S;
  int bx = rest / S;
  int w = threadIdx.x >> 6, lane = threadIdx.x & 63;
  int q = lane >> 4, l = lane & 15;
  int rowbase = bx * 128 + w * 32;
  int trb = rowbase >> 4;            // 16-row tile index (covers trb, trb+1)
  const float* f2p = f2g + head * NN;
  size_t headJB = (size_t)head * (NN / 32);
  float f1c0 = f1g[head * NN + rowbase + l] * 1.44269504f;
  float f1c1 = f1g[head * NN + rowbase + 16 + l] * 1.44269504f;

  short8 ones;
#pragma unroll
  for (int i = 0; i < 8; i++) ones[i] = (short)0x3F80;

  float4v acc[2][NCT];
#pragma unroll
  for (int rt = 0; rt < 2; rt++)
#pragma unroll
    for (int ct = 0; ct < NCT; ct++) { float4v z = {0.f, 0.f, 0.f, 0.f}; acc[rt][ct] = z; }
  float4v accd[2];
  accd[0] = float4v{0.f, 0.f, 0.f, 0.f};
  accd[1] = float4v{0.f, 0.f, 0.f, 0.f};

  const unsigned short* mBase = maskF + (size_t)trb * (NN / 32) * 512 + lane * 8;
  const size_t mRowTile = (size_t)(NN / 32) * 512;

  int j0 = js * JCH;
  short8 mm0 = *(const short8*)(mBase + (size_t)(j0 >> 5) * 512);
  short8 mm1 = *(const short8*)(mBase + mRowTile + (size_t)(j0 >> 5) * 512);
  float4v fa = *(const float4v*)(f2p + j0 + q * 8);
  float4v fb = *(const float4v*)(f2p + j0 + q * 8 + 4);

  for (int jb = j0; jb < j0 + JCH; jb += 32) {
    short8 mc0 = mm0, mc1 = mm1;
    float4v fac = fa, fbc = fb;
    int jn = (jb + 32 < j0 + JCH) ? jb + 32 : j0;
    mm0 = *(const short8*)(mBase + (size_t)(jn >> 5) * 512);
    mm1 = *(const short8*)(mBase + mRowTile + (size_t)(jn >> 5) * 512);
    fa = *(const float4v*)(f2p + jn + q * 8);
    fb = *(const float4v*)(f2p + jn + q * 8 + 4);
    const unsigned short* bbase =
        WhTf + (headJB + (jb >> 5)) * (NCT * 512) + lane * 8;
    short8 bfr[NCT];
#pragma unroll
    for (int ct = 0; ct < NCT; ct++)   // coalesced 1KB fragment loads
      bfr[ct] = *(const short8*)(bbase + ct * 512);

    float p0[8], p1[8];
#pragma unroll
    for (int i = 0; i < 8; i++) {
      float fv = (i < 4) ? fac[i] : fbc[i - 4];
      float t0 = fmaf(fv, 1.44269504f, f1c0);               // log2e*(f1+f2)
      t0 = __builtin_amdgcn_fmed3f(t0, 0.2f * t0, 43.f);    // leaky+clamp
      p0[i] = exp2f(t0);
      float t1 = fmaf(fv, 1.44269504f, f1c1);
      t1 = __builtin_amdgcn_fmed3f(t1, 0.2f * t1, 43.f);
      p1[i] = exp2f(t1);
    }
    union PK { short8 s8; unsigned u[4]; } u0, u1, m0v, m1v;
    m0v.s8 = mc0; m1v.s8 = mc1;
    union { __hip_bfloat162 b2[4]; short8 s8; } t0p, t1p;
#pragma unroll
    for (int k = 0; k < 4; k++) {
      t0p.b2[k] = __float22bfloat162_rn({p0[2 * k], p0[2 * k + 1]});
      t1p.b2[k] = __float22bfloat162_rn({p1[2 * k], p1[2 * k + 1]});
    }
    u0.s8 = t0p.s8; u1.s8 = t1p.s8;
#pragma unroll
    for (int k = 0; k < 4; k++) {      // mask: bitwise AND on packed bf16
      u0.u[k] &= m0v.u[k];
      u1.u[k] &= m1v.u[k];
    }
    accd[0] = __builtin_amdgcn_mfma_f32_16x16x32_bf16(u0.s8, ones, accd[0], 0, 0, 0);
    accd[1] = __builtin_amdgcn_mfma_f32_16x16x32_bf16(u1.s8, ones, accd[1], 0, 0, 0);
#pragma unroll
    for (int ct = 0; ct < NCT; ct++) {
      acc[0][ct] = __builtin_amdgcn_mfma_f32_16x16x32_bf16(u0.s8, bfr[ct], acc[0][ct], 0, 0, 0);
      acc[1][ct] = __builtin_amdgcn_mfma_f32_16x16x32_bf16(u1.s8, bfr[ct], acc[1][ct], 0, 0, 0);
    }
  }

  size_t slab = (size_t)(js * NH + head);
  if (l == 0) {   // accd replicated across cols; lanes 0,16,32,48 cover rows
#pragma unroll
    for (int rt = 0; rt < 2; rt++)
#pragma unroll
      for (int reg = 0; reg < 4; reg++)
        pden[slab * NN + rowbase + rt * 16 + q * 4 + reg] = accd[rt][reg];
  }
  // numerator: bf16, MFMA-fragment order -> fully coalesced 512B stores
#pragma unroll
  for (int rt = 0; rt < 2; rt++)
#pragma unroll
    for (int ct = 0; ct < NCT; ct++) {
      ushort4v u;
      u.x = f2bf(acc[rt][ct].x); u.y = f2bf(acc[rt][ct].y);
      u.z = f2bf(acc[rt][ct].z); u.w = f2bf(acc[rt][ct].w);
      size_t cidx = ((slab * (NN / 16) + trb + rt) * NCT + ct) * 256 + lane * 4;
      *(ushort4v*)(pnum + cidx) = u;
    }
}

// ---- combine partials (bf16 frag-order): divide, ELU, store layer layout ----
template<int DCOL, int S>
__global__ __launch_bounds__(256) void k_attn_reduce(
    const unsigned short* __restrict__ pnum, const float* __restrict__ pden,
    void* __restrict__ outg, long outHeadOff, int outRowStride, int NH,
    const int* __restrict__ flag, int finalOut) {
  constexpr int NCT = DCOL / 16;
  int tid = blockIdx.x * 256 + threadIdx.x;   // over NH*NN*DCOL
  int h = tid / (NN * DCOL);
  int e = tid % (NN * DCOL);
  int tile = e >> 8, r4 = e & 255;
  int ct = tile % NCT, tr = tile / NCT;
  int lane = r4 >> 2, reg = r4 & 3;
  int q = lane >> 4, l = lane & 15;
  int row = tr * 16 + q * 4 + reg;
  int col = ct * 16 + l;
  float sn = 0.f, sd = 0.f;
#pragma unroll
  for (int js = 0; js < S; js++) {
    size_t sl = (size_t)(js * NH + h);
    sn += bf2f(pnum[sl * (size_t)(NN * DCOL) + e]);   // coalesced
    sd += pden[sl * NN + row];
  }
  float v = sd > 0.f ? sn / sd : 0.f;
  v = v > 0.f ? v : expm1f(v);                    // ELU
  size_t idx = (size_t)h * outHeadOff + (size_t)row * outRowStride + col;
  if (finalOut && *flag == 0) ((float*)outg)[idx] = v;
  else ((unsigned short*)outg)[idx] = f2bf(v);
}

extern "C" void kernel_launch(void* const* d_in, const int* in_sizes, int n_in,
                              void* d_out, int out_size, void* d_ws, size_t ws_size,
                              hipStream_t stream) {
  const void* x     = d_in[0];
  const void* adj   = d_in[1];
  const int*  obs   = (const int*)d_in[2];
  // d_in[3] s_mat unused (method='base')
  const void* theta = d_in[4];
  const void* W0    = d_in[5];
  const void* a0    = d_in[6];
  const void* W1    = d_in[7];
  const void* a1    = d_in[8];
  const void* Wo    = d_in[9];
  const void* ao    = d_in[10];

  char* ws = (char*)d_ws;
  size_t off = 0;
  auto alloc = [&](size_t bytes) { void* p = ws + off; off += (bytes + 255) & ~(size_t)255; return p; };
  int*            flag  = (int*)alloc(4);
  unsigned short* maskF = (unsigned short*)alloc((size_t)(NN / 16) * (NN / 32) * 512 * 2);
  unsigned short* h_bf  = (unsigned short*)alloc((size_t)NN * 256 * 2);
  unsigned short* WhTf  = (unsigned short*)alloc((size_t)HH * 128 * NN * 2);
  float*          f1    = (float*)alloc((size_t)HH * NN * 4);
  float*          f2    = (float*)alloc((size_t)HH * NN * 4);
  unsigned short* h0    = (unsigned short*)alloc((size_t)HH * NN * 128 * 2);
  unsigned short* hc    = (unsigned short*)alloc((size_t)NN * 1024 * 2);
  unsigned short* W0T   = (unsigned short*)alloc((size_t)HH * 128 * 256 * 2);
  unsigned short* W1T   = (unsigned short*)alloc((size_t)HH * 128 * 128 * 2);
  unsigned short* WoT   = (unsigned short*)alloc((size_t)64 * 1024 * 2);
  unsigned short* WhoTf = (unsigned short*)alloc((size_t)64 * NN * 2);
  float*          fo1   = (float*)alloc((size_t)NN * 4);
  float*          fo2   = (float*)alloc((size_t)NN * 4);
  float*          gpart = (float*)alloc((size_t)4 * 64 * NN * 4);

  // partial buffers: bf16 numerators (frag order) + fp32 denominators
  size_t fixedEnd = off;
  auto needBytes = [&](int s) {
    size_t slabs = (size_t)((s * HH > 32) ? s * HH : 32);
    return fixedEnd + (size_t)s * HH * NN * 128 * 2 + slabs * NN * 4 + 8192;
  };
  int S = (needBytes(8) <= ws_size) ? 8 : (needBytes(4) <= ws_size) ? 4 : 2;
  unsigned short* pnum = (unsigned short*)alloc((size_t)S * HH * NN * 128 * 2);
  float* pden = (float*)alloc((size_t)((S * HH > 32) ? S * HH : 32) * NN * 4);

  k_detect<<<1, 256, 0, stream>>>((const unsigned*)adj, flag);
  k_maskfrag<<<(NN / 16) * (NN / 32) / 4, 256, 0, stream>>>(adj, flag, maskF);
  k_merge<<<dim3(NN), 256, 0, stream>>>(x, obs, theta, flag, h_bf);
  k_transpose<<<dim3(8, 16, HH), 256, 0, stream>>>(W0, flag, W0T, 256, 128);
  k_transpose<<<dim3(8, 8, HH), 256, 0, stream>>>(W1, flag, W1T, 128, 128);
  k_transpose<<<dim3(4, 64, 1), 256, 0, stream>>>(Wo, flag, WoT, 1024, 64);

  // ---- layer 0 ----
  k_gemm_fused<256><<<dim3(NN / 32, HH), 256, 0, stream>>>(h_bf, W0T, WhTf, 0, 128 * 256);
  k_f12f<128><<<dim3(NN / 128, HH), 256, 0, stream>>>(WhTf, a0, flag, f1, f2);
  switch (S) {
    case 8:
      k_attn_part<128, 8><<<(NN / 128) * 8 * HH, 256, 0, stream>>>(maskF, f1, f2, WhTf, pnum, pden, HH);
      k_attn_reduce<128, 8><<<HH * NN * 128 / 256, 256, 0, stream>>>(pnum, pden, h0, (long)NN * 128, 128, HH, flag, 0);
      break;
    case 4:
      k_attn_part<128, 4><<<(NN / 128) * 4 * HH, 256, 0, stream>>>(maskF, f1, f2, WhTf, pnum, pden, HH);
      k_attn_reduce<128, 4><<<HH * NN * 128 / 256, 256, 0, stream>>>(pnum, pden, h0, (long)NN * 128, 128, HH, flag, 0);
      break;
    default:
      k_attn_part<128, 2><<<(NN / 128) * 2 * HH, 256, 0, stream>>>(maskF, f1, f2, WhTf, pnum, pden, HH);
      k_attn_reduce<128, 2><<<HH * NN * 128 / 256, 256, 0, stream>>>(pnum, pden, h0, (long)NN * 128, 128, HH, flag, 0);
  }
  // ---- layer 1 ----
  k_gemm_fused<128><<<dim3(NN / 32, HH), 256, 0, stream>>>(h0, W1T, WhTf, (long)NN * 128, 128 * 128);
  k_f12f<128><<<dim3(NN / 128, HH), 256, 0, stream>>>(WhTf, a1, flag, f1, f2);
  switch (S) {
    case 8:
      k_attn_part<128, 8><<<(NN / 128) * 8 * HH, 256, 0, stream>>>(maskF, f1, f2, WhTf, pnum, pden, HH);
      k_attn_reduce<128, 8><<<HH * NN * 128 / 256, 256, 0, stream>>>(pnum, pden, hc, 128, 1024, HH, flag, 0);
      break;
    case 4:
      k_attn_part<128, 4><<<(NN / 128) * 4 * HH, 256, 0, stream>>>(maskF, f1, f2, WhTf, pnum, pden, HH);
      k_attn_reduce<128, 4><<<HH * NN * 128 / 256, 256, 0, stream>>>(pnum, pden, hc, 128, 1024, HH, flag, 0);
      break;
    default:
      k_attn_part<128, 2><<<(NN / 128) * 2 * HH, 256, 0, stream>>>(maskF, f1, f2, WhTf, pnum, pden, HH);
      k_attn_reduce<128, 2><<<HH * NN * 128 / 256, 256, 0, stream>>>(pnum, pden, hc, 128, 1024, HH, flag, 0);
  }
  // ---- output layer ----
  k_gemm_out<1024, 4><<<dim3(NN / 16, 4), 256, 0, stream>>>(hc, WoT, gpart);
  k_gemm_red<4><<<64 * NN / 256, 256, 0, stream>>>(gpart, WhoTf);
  k_f12f<64><<<dim3(NN / 128, 1), 256, 0, stream>>>(WhoTf, ao, flag, fo1, fo2);
  k_attn_part<64, 32><<<(NN / 128) * 32, 256, 0, stream>>>(maskF, fo1, fo2, WhoTf, pnum, pden, 1);
  k_attn_reduce<64, 32><<<NN * 64 / 256, 256, 0, stream>>>(pnum, pden, d_out, 0, 64, 1, flag, 1);
}

// Round 12
// 368.368 us; speedup vs baseline: 1.0645x; 1.0645x over previous
//
#include <hip/hip_runtime.h>
#include <hip/hip_bf16.h>

#define NN 3072
#define NWORD 96   // u32 mask words per row
#define HH 8

typedef short short8 __attribute__((ext_vector_type(8)));
typedef float float4v __attribute__((ext_vector_type(4)));
typedef unsigned short ushort4v __attribute__((ext_vector_type(4)));

__device__ __forceinline__ float bf2f(unsigned short u) {
  union { unsigned u; float f; } v; v.u = ((unsigned)u) << 16; return v.f;
}
__device__ __forceinline__ unsigned short f2bf(float f) {
  union { float f; unsigned u; } v; v.f = f;
  unsigned r = v.u + 0x7fffu + ((v.u >> 16) & 1u);
  return (unsigned short)(r >> 16);
}
// flag==1 -> buffers are bf16; flag==0 -> fp32
__device__ __forceinline__ float ldin(const void* p, size_t i, int isbf) {
  return isbf ? bf2f(((const unsigned short*)p)[i]) : ((const float*)p)[i];
}

// ---- dtype detect: adj is exactly {0.0,1.0}; fp32 words have low16==0 always ----
__global__ __launch_bounds__(256) void k_detect(const unsigned* __restrict__ aw,
                                                int* __restrict__ flag) {
  __shared__ int s;
  if (threadIdx.x == 0) s = 0;
  __syncthreads();
  int any = 0;
  for (int i = threadIdx.x; i < 16384; i += 256)
    any |= ((aw[i] & 0xFFFFu) != 0u);
  if (any) s = 1;   // benign race
  __syncthreads();
  if (threadIdx.x == 0) *flag = s;
}

// ---- build TRANSPOSED bitmask: maskT[word][row] (1.2 MB, L2-resident) ----
__global__ __launch_bounds__(256) void k_mask(const void* __restrict__ adj,
                                              const int* __restrict__ flag,
                                              unsigned* __restrict__ maskT) {
  int isbf = *flag;
  int row = blockIdx.y;
  int j = blockIdx.x * 256 + threadIdx.x;
  bool pred = ldin(adj, (size_t)row * NN + j, isbf) != 0.f;
  unsigned long long b = __ballot(pred);
  int lane = threadIdx.x & 63;
  int word = blockIdx.x * 8 + (threadIdx.x >> 6) * 2;   // 0..95 within row
  if (lane == 0) maskT[(size_t)word * NN + row] = (unsigned)b;
  else if (lane == 32) maskT[(size_t)(word + 1) * NN + row] = (unsigned)(b >> 32);
}

// ---- mergeState: h = x + (obs==1) * theta ----
__global__ __launch_bounds__(256) void k_merge(const void* __restrict__ x,
                                               const int* __restrict__ obs,
                                               const void* __restrict__ theta,
                                               const int* __restrict__ flag,
                                               unsigned short* __restrict__ h) {
  int isbf = *flag;
  int i = blockIdx.x * 256 + threadIdx.x;
  int row = i >> 8, c = i & 255;
  float v = ldin(x, i, isbf);
  if (obs[row] == 1) v += ldin(theta, c, isbf);
  h[i] = f2bf(v);
}

// ---- batched 16x16 LDS transpose: in[b][R][C] -> out[b][C][R] (out bf16) ----
__global__ __launch_bounds__(256) void k_transpose(const void* __restrict__ in,
                                                   const int* __restrict__ flag,
                                                   unsigned short* __restrict__ out,
                                                   int R, int C) {
  __shared__ __align__(16) unsigned short tile[16][17];
  int isbf = *flag;
  int b = blockIdx.z;
  size_t base = (size_t)b * R * C;
  unsigned short* pout = out + base;
  int r0 = blockIdx.y * 16, c0 = blockIdx.x * 16;
  int tc = threadIdx.x & 15, tr = threadIdx.x >> 4;
  tile[tr][tc] = f2bf(ldin(in, base + (size_t)(r0 + tr) * C + (c0 + tc), isbf));
  __syncthreads();
  pout[(size_t)(c0 + tr) * R + (r0 + tc)] = tile[tc][tr];
}

// ---- fused GEMM: 32 rows x 128 cols per block; epilogue writes WhTf directly
//      in MFMA-B-fragment order via per-wave LDS transpose (no scatter/repack) ----
template<int K>
__global__ __launch_bounds__(256) void k_gemm_fused(const unsigned short* __restrict__ A,
                                                    const unsigned short* __restrict__ WT,
                                                    unsigned short* __restrict__ WhTf,
                                                    long aOff, long wOff) {
  __shared__ __align__(16) unsigned short tile[4][2][32][17];
  int head = blockIdx.y;
  A += (size_t)head * aOff; WT += (size_t)head * wOff;
  int jb = blockIdx.x;                 // 32-row tile index (j-block for attn)
  int rowbase = jb * 32;
  int t = threadIdx.x;
  int w = t >> 6, lane = t & 63;
  int q = lane >> 4, l = lane & 15;
  int colbase = w * 32;
  float4v acc[2][2];
#pragma unroll
  for (int rt = 0; rt < 2; rt++)
#pragma unroll
    for (int ct = 0; ct < 2; ct++) { float4v z = {0.f, 0.f, 0.f, 0.f}; acc[rt][ct] = z; }

  for (int kb = 0; kb < K; kb += 32) {
    short8 af[2], bfr[2];
#pragma unroll
    for (int rt = 0; rt < 2; rt++)
      af[rt] = *(const short8*)(A + (size_t)(rowbase + rt * 16 + l) * K + kb + q * 8);
#pragma unroll
    for (int ct = 0; ct < 2; ct++)
      bfr[ct] = *(const short8*)(WT + (size_t)(colbase + ct * 16 + l) * K + kb + q * 8);
#pragma unroll
    for (int rt = 0; rt < 2; rt++)
#pragma unroll
      for (int ct = 0; ct < 2; ct++)
        acc[rt][ct] = __builtin_amdgcn_mfma_f32_16x16x32_bf16(af[rt], bfr[ct], acc[rt][ct], 0, 0, 0);
  }
#pragma unroll
  for (int rt = 0; rt < 2; rt++)
#pragma unroll
    for (int ct = 0; ct < 2; ct++)
#pragma unroll
      for (int reg = 0; reg < 4; reg++)
        tile[w][ct][rt * 16 + q * 4 + reg][l] = f2bf(acc[rt][ct][reg]);
  __syncthreads();
#pragma unroll
  for (int ct = 0; ct < 2; ct++) {
    short8 r8;
#pragma unroll
    for (int i = 0; i < 8; i++) r8[i] = tile[w][ct][q * 8 + i][l];
    size_t chunk = ((size_t)head * (NN / 32) + jb) * 8 + (w * 2 + ct);
    *(short8*)(WhTf + chunk * 512 + lane * 8) = r8;
  }
}

// ---- out-layer GEMM, K split across blocks into fp32 partials ----
template<int K, int KS>
__global__ __launch_bounds__(256) void k_gemm_out(const unsigned short* __restrict__ A,
                                                  const unsigned short* __restrict__ WT,
                                                  float* __restrict__ gpart) {
  constexpr int KC = K / KS;
  int ks = blockIdx.y;
  int rowbase = blockIdx.x * 16;
  int t = threadIdx.x;
  int w = t >> 6, lane = t & 63;
  int q = lane >> 4, l = lane & 15;
  int colbase = w * 16;
  float4v acc = {0.f, 0.f, 0.f, 0.f};
  for (int kb = ks * KC; kb < ks * KC + KC; kb += 32) {
    short8 af = *(const short8*)(A + (size_t)(rowbase + l) * K + kb + q * 8);
    short8 bfr = *(const short8*)(WT + (size_t)(colbase + l) * K + kb + q * 8);
    acc = __builtin_amdgcn_mfma_f32_16x16x32_bf16(af, bfr, acc, 0, 0, 0);
  }
#pragma unroll
  for (int reg = 0; reg < 4; reg++) {
    int r = rowbase + q * 4 + reg;
    int n = colbase + l;
    gpart[((size_t)ks * 64 + n) * NN + r] = acc[reg];
  }
}

// ---- combine K-split partials, emit WhoTf in fragment order (DC=64) ----
template<int KS>
__global__ __launch_bounds__(256) void k_gemm_red(const float* __restrict__ gpart,
                                                  unsigned short* __restrict__ WhoTf) {
  int tid = blockIdx.x * 256 + threadIdx.x;   // over 64*NN
  int r = tid % NN, n = tid / NN;
  float s = 0.f;
#pragma unroll
  for (int ks = 0; ks < KS; ks++) s += gpart[((size_t)ks * 64 + n) * NN + r];
  int jb = r >> 5, q = (r >> 3) & 3, i = r & 7, ct = n >> 4, l = n & 15;
  WhoTf[((size_t)(jb * 4 + ct)) * 512 + (q * 16 + l) * 8 + i] = f2bf(s);
}

// ---- f1/f2 from fragment-order WhTf: coalesced loads + shuffle reduce ----
template<int DC>
__global__ __launch_bounds__(256) void k_f12f(const unsigned short* __restrict__ WhTf,
                                              const void* __restrict__ avec,
                                              const int* __restrict__ flag,
                                              float* __restrict__ f1, float* __restrict__ f2) {
  constexpr int NCT = DC / 16;
  int isbf = *flag;
  int head = blockIdx.y;
  int w = threadIdx.x >> 6, lane = threadIdx.x & 63;
  int q = lane >> 4, l = lane & 15;
  int jbIdx = blockIdx.x * 4 + w;
  size_t abase = (size_t)head * 2 * DC;
  float s1[8], s2[8];
#pragma unroll
  for (int i = 0; i < 8; i++) { s1[i] = 0.f; s2[i] = 0.f; }
#pragma unroll
  for (int ct = 0; ct < NCT; ct++) {
    short8 v = *(const short8*)(WhTf + (((size_t)head * (NN / 32) + jbIdx) * NCT + ct) * 512 + lane * 8);
    float a1v = ldin(avec, abase + ct * 16 + l, isbf);
    float a2v = ldin(avec, abase + DC + ct * 16 + l, isbf);
#pragma unroll
    for (int i = 0; i < 8; i++) {
      float f = bf2f((unsigned short)v[i]);
      s1[i] += f * a1v;
      s2[i] += f * a2v;
    }
  }
#pragma unroll
  for (int d = 1; d < 16; d <<= 1)
#pragma unroll
    for (int i = 0; i < 8; i++) {
      s1[i] += __shfl_xor(s1[i], d, 64);
      s2[i] += __shfl_xor(s2[i], d, 64);
    }
  if (l == 0) {
    int r = jbIdx * 32 + q * 8;
#pragma unroll
    for (int i = 0; i < 8; i++) {
      f1[head * NN + r + i] = s1[i];
      f2[head * NN + r + i] = s2[i];
    }
  }
}

// ---- attention partial (r10 measured-best): barrier-free, LDS-free;
//      full-DCOL waves, transposed 1-bit mask, ones-MFMA denominator,
//      bf16 frag-order partials, head pinned to XCD via blockIdx.x % NH ----
template<int DCOL, int S>
__global__ __launch_bounds__(256, 4) void k_attn_part(
    const unsigned* __restrict__ maskT,
    const float* __restrict__ f1g, const float* __restrict__ f2g,
    const unsigned short* __restrict__ WhTf,
    unsigned short* __restrict__ pnum, float* __restrict__ pden, int NH) {
  constexpr int NCT = DCOL / 16;
  constexpr int JCH = NN / S;
  int blk = blockIdx.x;
  int head = blk % NH;               // lowest bits -> XCD pin for NH=8
  int rest = blk / NH;
  int js = rest % S;
  int bx = rest / S;
  int w = threadIdx.x >> 6, lane = threadIdx.x & 63;
  int q = lane >> 4, l = lane & 15;
  int rowbase = bx * 128 + w * 32;
  const float* f2p = f2g + head * NN;
  size_t headJB = (size_t)head * (NN / 32);
  float f1c0 = f1g[head * NN + rowbase + l] * 1.44269504f;
  float f1c1 = f1g[head * NN + rowbase + 16 + l] * 1.44269504f;

  short8 ones;
#pragma unroll
  for (int i = 0; i < 8; i++) ones[i] = (short)0x3F80;

  float4v acc[2][NCT];
#pragma unroll
  for (int rt = 0; rt < 2; rt++)
#pragma unroll
    for (int ct = 0; ct < NCT; ct++) { float4v z = {0.f, 0.f, 0.f, 0.f}; acc[rt][ct] = z; }
  float4v accd[2];
  accd[0] = float4v{0.f, 0.f, 0.f, 0.f};
  accd[1] = float4v{0.f, 0.f, 0.f, 0.f};

  int j0 = js * JCH;
  unsigned mw0 = maskT[(size_t)(j0 >> 5) * NN + rowbase + l];
  unsigned mw1 = maskT[(size_t)(j0 >> 5) * NN + rowbase + 16 + l];
  float4v fa = *(const float4v*)(f2p + j0 + q * 8);
  float4v fb = *(const float4v*)(f2p + j0 + q * 8 + 4);

  for (int jb = j0; jb < j0 + JCH; jb += 32) {
    unsigned mwc0 = mw0 >> (q * 8);
    unsigned mwc1 = mw1 >> (q * 8);
    float4v fac = fa, fbc = fb;
    int jn = (jb + 32 < j0 + JCH) ? jb + 32 : j0;
    mw0 = maskT[(size_t)(jn >> 5) * NN + rowbase + l];
    mw1 = maskT[(size_t)(jn >> 5) * NN + rowbase + 16 + l];
    fa = *(const float4v*)(f2p + jn + q * 8);
    fb = *(const float4v*)(f2p + jn + q * 8 + 4);
    const unsigned short* bbase =
        WhTf + (headJB + (jb >> 5)) * (NCT * 512) + lane * 8;
    short8 bfr[NCT];
#pragma unroll
    for (int ct = 0; ct < NCT; ct++)   // coalesced 1KB fragment loads
      bfr[ct] = *(const short8*)(bbase + ct * 512);

    float p0[8], p1[8];
#pragma unroll
    for (int i = 0; i < 8; i++) {
      float fv = (i < 4) ? fac[i] : fbc[i - 4];
      float t0 = fmaf(fv, 1.44269504f, f1c0);               // log2e*(f1+f2)
      t0 = __builtin_amdgcn_fmed3f(t0, 0.2f * t0, 43.f);    // leaky+clamp
      t0 = (mwc0 & (1u << i)) ? t0 : -200.f;
      p0[i] = exp2f(t0);
      float t1 = fmaf(fv, 1.44269504f, f1c1);
      t1 = __builtin_amdgcn_fmed3f(t1, 0.2f * t1, 43.f);
      t1 = (mwc1 & (1u << i)) ? t1 : -200.f;
      p1[i] = exp2f(t1);
    }
    union { __hip_bfloat162 b2[4]; short8 s8; } u0, u1;
#pragma unroll
    for (int k = 0; k < 4; k++) {
      u0.b2[k] = __float22bfloat162_rn({p0[2 * k], p0[2 * k + 1]});
      u1.b2[k] = __float22bfloat162_rn({p1[2 * k], p1[2 * k + 1]});
    }
    accd[0] = __builtin_amdgcn_mfma_f32_16x16x32_bf16(u0.s8, ones, accd[0], 0, 0, 0);
    accd[1] = __builtin_amdgcn_mfma_f32_16x16x32_bf16(u1.s8, ones, accd[1], 0, 0, 0);
#pragma unroll
    for (int ct = 0; ct < NCT; ct++) {
      acc[0][ct] = __builtin_amdgcn_mfma_f32_16x16x32_bf16(u0.s8, bfr[ct], acc[0][ct], 0, 0, 0);
      acc[1][ct] = __builtin_amdgcn_mfma_f32_16x16x32_bf16(u1.s8, bfr[ct], acc[1][ct], 0, 0, 0);
    }
  }

  size_t slab = (size_t)(js * NH + head);
  if (l == 0) {   // accd replicated across cols; lanes 0,16,32,48 cover rows
#pragma unroll
    for (int rt = 0; rt < 2; rt++)
#pragma unroll
      for (int reg = 0; reg < 4; reg++)
        pden[slab * NN + rowbase + rt * 16 + q * 4 + reg] = accd[rt][reg];
  }
  // numerator: bf16, MFMA-fragment order -> fully coalesced 512B stores
  int trb = rowbase >> 4;              // global 16-row tile index
#pragma unroll
  for (int rt = 0; rt < 2; rt++)
#pragma unroll
    for (int ct = 0; ct < NCT; ct++) {
      ushort4v u;
      u.x = f2bf(acc[rt][ct].x); u.y = f2bf(acc[rt][ct].y);
      u.z = f2bf(acc[rt][ct].z); u.w = f2bf(acc[rt][ct].w);
      size_t cidx = ((slab * (NN / 16) + trb + rt) * NCT + ct) * 256 + lane * 4;
      *(ushort4v*)(pnum + cidx) = u;
    }
}

// ---- combine partials (bf16 frag-order): divide, ELU, store layer layout ----
template<int DCOL, int S>
__global__ __launch_bounds__(256) void k_attn_reduce(
    const unsigned short* __restrict__ pnum, const float* __restrict__ pden,
    void* __restrict__ outg, long outHeadOff, int outRowStride, int NH,
    const int* __restrict__ flag, int finalOut) {
  constexpr int NCT = DCOL / 16;
  int tid = blockIdx.x * 256 + threadIdx.x;   // over NH*NN*DCOL
  int h = tid / (NN * DCOL);
  int e = tid % (NN * DCOL);
  int tile = e >> 8, r4 = e & 255;
  int ct = tile % NCT, tr = tile / NCT;
  int lane = r4 >> 2, reg = r4 & 3;
  int q = lane >> 4, l = lane & 15;
  int row = tr * 16 + q * 4 + reg;
  int col = ct * 16 + l;
  float sn = 0.f, sd = 0.f;
#pragma unroll
  for (int js = 0; js < S; js++) {
    size_t sl = (size_t)(js * NH + h);
    sn += bf2f(pnum[sl * (size_t)(NN * DCOL) + e]);   // coalesced
    sd += pden[sl * NN + row];
  }
  float v = sd > 0.f ? sn / sd : 0.f;
  v = v > 0.f ? v : expm1f(v);                    // ELU
  size_t idx = (size_t)h * outHeadOff + (size_t)row * outRowStride + col;
  if (finalOut && *flag == 0) ((float*)outg)[idx] = v;
  else ((unsigned short*)outg)[idx] = f2bf(v);
}

extern "C" void kernel_launch(void* const* d_in, const int* in_sizes, int n_in,
                              void* d_out, int out_size, void* d_ws, size_t ws_size,
                              hipStream_t stream) {
  const void* x     = d_in[0];
  const void* adj   = d_in[1];
  const int*  obs   = (const int*)d_in[2];
  // d_in[3] s_mat unused (method='base')
  const void* theta = d_in[4];
  const void* W0    = d_in[5];
  const void* a0    = d_in[6];
  const void* W1    = d_in[7];
  const void* a1    = d_in[8];
  const void* Wo    = d_in[9];
  const void* ao    = d_in[10];

  char* ws = (char*)d_ws;
  size_t off = 0;
  auto alloc = [&](size_t bytes) { void* p = ws + off; off += (bytes + 255) & ~(size_t)255; return p; };
  int*            flag  = (int*)alloc(4);
  unsigned*       maskT = (unsigned*)alloc((size_t)NN * NWORD * 4);
  unsigned short* h_bf  = (unsigned short*)alloc((size_t)NN * 256 * 2);
  unsigned short* WhTf  = (unsigned short*)alloc((size_t)HH * 128 * NN * 2);
  float*          f1    = (float*)alloc((size_t)HH * NN * 4);
  float*          f2    = (float*)alloc((size_t)HH * NN * 4);
  unsigned short* h0    = (unsigned short*)alloc((size_t)HH * NN * 128 * 2);
  unsigned short* hc    = (unsigned short*)alloc((size_t)NN * 1024 * 2);
  unsigned short* W0T   = (unsigned short*)alloc((size_t)HH * 128 * 256 * 2);
  unsigned short* W1T   = (unsigned short*)alloc((size_t)HH * 128 * 128 * 2);
  unsigned short* WoT   = (unsigned short*)alloc((size_t)64 * 1024 * 2);
  unsigned short* WhoTf = (unsigned short*)alloc((size_t)64 * NN * 2);
  float*          fo1   = (float*)alloc((size_t)NN * 4);
  float*          fo2   = (float*)alloc((size_t)NN * 4);
  float*          gpart = (float*)alloc((size_t)4 * 64 * NN * 4);

  // partial buffers: bf16 numerators (frag order) + fp32 denominators
  size_t fixedEnd = off;
  auto needBytes = [&](int s) {
    size_t slabs = (size_t)((s * HH > 32) ? s * HH : 32);
    return fixedEnd + (size_t)s * HH * NN * 128 * 2 + slabs * NN * 4 + 8192;
  };
  int S = (needBytes(8) <= ws_size) ? 8 : (needBytes(4) <= ws_size) ? 4 : 2;
  unsigned short* pnum = (unsigned short*)alloc((size_t)S * HH * NN * 128 * 2);
  float* pden = (float*)alloc((size_t)((S * HH > 32) ? S * HH : 32) * NN * 4);

  k_detect<<<1, 256, 0, stream>>>((const unsigned*)adj, flag);
  k_mask<<<dim3(12, NN), 256, 0, stream>>>(adj, flag, maskT);
  k_merge<<<dim3(NN), 256, 0, stream>>>(x, obs, theta, flag, h_bf);
  k_transpose<<<dim3(8, 16, HH), 256, 0, stream>>>(W0, flag, W0T, 256, 128);
  k_transpose<<<dim3(8, 8, HH), 256, 0, stream>>>(W1, flag, W1T, 128, 128);
  k_transpose<<<dim3(4, 64, 1), 256, 0, stream>>>(Wo, flag, WoT, 1024, 64);

  // ---- layer 0 ----
  k_gemm_fused<256><<<dim3(NN / 32, HH), 256, 0, stream>>>(h_bf, W0T, WhTf, 0, 128 * 256);
  k_f12f<128><<<dim3(NN / 128, HH), 256, 0, stream>>>(WhTf, a0, flag, f1, f2);
  switch (S) {
    case 8:
      k_attn_part<128, 8><<<(NN / 128) * 8 * HH, 256, 0, stream>>>(maskT, f1, f2, WhTf, pnum, pden, HH);
      k_attn_reduce<128, 8><<<HH * NN * 128 / 256, 256, 0, stream>>>(pnum, pden, h0, (long)NN * 128, 128, HH, flag, 0);
      break;
    case 4:
      k_attn_part<128, 4><<<(NN / 128) * 4 * HH, 256, 0, stream>>>(maskT, f1, f2, WhTf, pnum, pden, HH);
      k_attn_reduce<128, 4><<<HH * NN * 128 / 256, 256, 0, stream>>>(pnum, pden, h0, (long)NN * 128, 128, HH, flag, 0);
      break;
    default:
      k_attn_part<128, 2><<<(NN / 128) * 2 * HH, 256, 0, stream>>>(maskT, f1, f2, WhTf, pnum, pden, HH);
      k_attn_reduce<128, 2><<<HH * NN * 128 / 256, 256, 0, stream>>>(pnum, pden, h0, (long)NN * 128, 128, HH, flag, 0);
  }
  // ---- layer 1 ----
  k_gemm_fused<128><<<dim3(NN / 32, HH), 256, 0, stream>>>(h0, W1T, WhTf, (long)NN * 128, 128 * 128);
  k_f12f<128><<<dim3(NN / 128, HH), 256, 0, stream>>>(WhTf, a1, flag, f1, f2);
  switch (S) {
    case 8:
      k_attn_part<128, 8><<<(NN / 128) * 8 * HH, 256, 0, stream>>>(maskT, f1, f2, WhTf, pnum, pden, HH);
      k_attn_reduce<128, 8><<<HH * NN * 128 / 256, 256, 0, stream>>>(pnum, pden, hc, 128, 1024, HH, flag, 0);
      break;
    case 4:
      k_attn_part<128, 4><<<(NN / 128) * 4 * HH, 256, 0, stream>>>(maskT, f1, f2, WhTf, pnum, pden, HH);
      k_attn_reduce<128, 4><<<HH * NN * 128 / 256, 256, 0, stream>>>(pnum, pden, hc, 128, 1024, HH, flag, 0);
      break;
    default:
      k_attn_part<128, 2><<<(NN / 128) * 2 * HH, 256, 0, stream>>>(maskT, f1, f2, WhTf, pnum, pden, HH);
      k_attn_reduce<128, 2><<<HH * NN * 128 / 256, 256, 0, stream>>>(pnum, pden, hc, 128, 1024, HH, flag, 0);
  }
  // ---- output layer ----
  k_gemm_out<1024, 4><<<dim3(NN / 16, 4), 256, 0, stream>>>(hc, WoT, gpart);
  k_gemm_red<4><<<64 * NN / 256, 256, 0, stream>>>(gpart, WhoTf);
  k_f12f<64><<<dim3(NN / 128, 1), 256, 0, stream>>>(WhoTf, ao, flag, fo1, fo2);
  k_attn_part<64, 32><<<(NN / 128) * 32, 256, 0, stream>>>(maskT, fo1, fo2, WhoTf, pnum, pden, 1);
  k_attn_reduce<64, 32><<<NN * 64 / 256, 256, 0, stream>>>(pnum, pden, d_out, 0, 64, 1, flag, 1);
}

// Round 13
// 307.257 us; speedup vs baseline: 1.2762x; 1.1989x over previous
//
#include <hip/hip_runtime.h>
#include <hip/hip_bf16.h>

#define NN 3072
#define NWORD 96
#define HH 8

typedef short short8 __attribute__((ext_vector_type(8)));
typedef float float4v __attribute__((ext_vector_type(4)));
typedef unsigned short ushort4v __attribute__((ext_vector_type(4)));

__device__ __forceinline__ float bf2f(unsigned short u) {
  union { unsigned u; float f; } v; v.u = ((unsigned)u) << 16; return v.f;
}
__device__ __forceinline__ unsigned short f2bf(float f) {
  union { float f; unsigned u; } v; v.f = f;
  unsigned r = v.u + 0x7fffu + ((v.u >> 16) & 1u);
  return (unsigned short)(r >> 16);
}
// flag==1 -> buffers are bf16; flag==0 -> fp32
__device__ __forceinline__ float ldin(const void* p, size_t i, int isbf) {
  return isbf ? bf2f(((const unsigned short*)p)[i]) : ((const float*)p)[i];
}

// ---- dtype detect ----
__global__ __launch_bounds__(256) void k_detect(const unsigned* __restrict__ aw,
                                                int* __restrict__ flag) {
  __shared__ int s;
  if (threadIdx.x == 0) s = 0;
  __syncthreads();
  int any = 0;
  for (int i = threadIdx.x; i < 16384; i += 256)
    any |= ((aw[i] & 0xFFFFu) != 0u);
  if (any) s = 1;   // benign race
  __syncthreads();
  if (threadIdx.x == 0) *flag = s;
}

// ---- build TRANSPOSED bitmask: maskT[word][row] (1.2 MB, L2-resident) ----
__global__ __launch_bounds__(256) void k_mask(const void* __restrict__ adj,
                                              const int* __restrict__ flag,
                                              unsigned* __restrict__ maskT) {
  int isbf = *flag;
  int row = blockIdx.y;
  int j = blockIdx.x * 256 + threadIdx.x;
  bool pred = ldin(adj, (size_t)row * NN + j, isbf) != 0.f;
  unsigned long long b = __ballot(pred);
  int lane = threadIdx.x & 63;
  int word = blockIdx.x * 8 + (threadIdx.x >> 6) * 2;
  if (lane == 0) maskT[(size_t)word * NN + row] = (unsigned)b;
  else if (lane == 32) maskT[(size_t)(word + 1) * NN + row] = (unsigned)(b >> 32);
}

// ---- prep: mergeState (blocks 0..NN) + all three weight transposes in one launch ----
__global__ __launch_bounds__(256) void k_prep(const void* __restrict__ x,
                                              const int* __restrict__ obs,
                                              const void* __restrict__ theta,
                                              const void* __restrict__ W0,
                                              const void* __restrict__ W1,
                                              const void* __restrict__ Wo,
                                              const int* __restrict__ flag,
                                              unsigned short* __restrict__ h_bf,
                                              unsigned short* __restrict__ W0T,
                                              unsigned short* __restrict__ W1T,
                                              unsigned short* __restrict__ WoT) {
  __shared__ __align__(16) unsigned short tile[16][17];
  int isbf = *flag;
  int t = threadIdx.x;
  int b = blockIdx.x;
  if (b < NN) {                          // mergeState
    int i = b * 256 + t;
    int row = i >> 8, c = i & 255;
    float v = ldin(x, i, isbf);
    if (obs[row] == 1) v += ldin(theta, c, isbf);
    h_bf[i] = f2bf(v);
    return;
  }
  b -= NN;
  const void* in; unsigned short* out; int R, C, r0, c0;
  if (b < 1024) {                        // W0: 8 heads x (16 x 8) tiles, 256x128
    int h = b >> 7, rem = b & 127;
    in = (const char*)W0 + (size_t)h * 256 * 128 * (isbf ? 2 : 4);
    out = W0T + (size_t)h * 256 * 128;
    R = 256; C = 128; r0 = (rem >> 3) * 16; c0 = (rem & 7) * 16;
  } else if (b < 1536) {                 // W1: 8 heads x (8 x 8), 128x128
    b -= 1024;
    int h = b >> 6, rem = b & 63;
    in = (const char*)W1 + (size_t)h * 128 * 128 * (isbf ? 2 : 4);
    out = W1T + (size_t)h * 128 * 128;
    R = 128; C = 128; r0 = (rem >> 3) * 16; c0 = (rem & 7) * 16;
  } else {                               // Wo: (64 x 4), 1024x64
    b -= 1536;
    in = Wo; out = WoT;
    R = 1024; C = 64; r0 = (b >> 2) * 16; c0 = (b & 3) * 16;
  }
  int tc = t & 15, tr = t >> 4;
  tile[tr][tc] = f2bf(ldin(in, (size_t)(r0 + tr) * C + (c0 + tc), isbf));
  __syncthreads();
  out[(size_t)(c0 + tr) * R + (r0 + tc)] = tile[tc][tr];
}

// ---- fused GEMM: 32 rows x 128 cols/block; writes WhTf in B-fragment order
//      via LDS transpose AND computes f1/f2 from the same LDS tile ----
template<int K>
__global__ __launch_bounds__(256) void k_gemm_fused(const unsigned short* __restrict__ A,
                                                    const unsigned short* __restrict__ WT,
                                                    unsigned short* __restrict__ WhTf,
                                                    long aOff, long wOff,
                                                    const void* __restrict__ avec,
                                                    const int* __restrict__ flag,
                                                    float* __restrict__ f1,
                                                    float* __restrict__ f2) {
  __shared__ __align__(16) unsigned short tile[4][2][32][17];
  __shared__ float avs[256];
  __shared__ float fp[2][8][32];
  int isbf = *flag;
  int head = blockIdx.y;
  A += (size_t)head * aOff; WT += (size_t)head * wOff;
  int jb = blockIdx.x;
  int rowbase = jb * 32;
  int t = threadIdx.x;
  int w = t >> 6, lane = t & 63;
  int q = lane >> 4, l = lane & 15;
  int colbase = w * 32;
  avs[t] = ldin(avec, (size_t)head * 256 + t, isbf);
  float4v acc[2][2];
#pragma unroll
  for (int rt = 0; rt < 2; rt++)
#pragma unroll
    for (int ct = 0; ct < 2; ct++) { float4v z = {0.f, 0.f, 0.f, 0.f}; acc[rt][ct] = z; }

  for (int kb = 0; kb < K; kb += 32) {
    short8 af[2], bfr[2];
#pragma unroll
    for (int rt = 0; rt < 2; rt++)
      af[rt] = *(const short8*)(A + (size_t)(rowbase + rt * 16 + l) * K + kb + q * 8);
#pragma unroll
    for (int ct = 0; ct < 2; ct++)
      bfr[ct] = *(const short8*)(WT + (size_t)(colbase + ct * 16 + l) * K + kb + q * 8);
#pragma unroll
    for (int rt = 0; rt < 2; rt++)
#pragma unroll
      for (int ct = 0; ct < 2; ct++)
        acc[rt][ct] = __builtin_amdgcn_mfma_f32_16x16x32_bf16(af[rt], bfr[ct], acc[rt][ct], 0, 0, 0);
  }
#pragma unroll
  for (int rt = 0; rt < 2; rt++)
#pragma unroll
    for (int ct = 0; ct < 2; ct++)
#pragma unroll
      for (int reg = 0; reg < 4; reg++)
        tile[w][ct][rt * 16 + q * 4 + reg][l] = f2bf(acc[rt][ct][reg]);
  __syncthreads();
  // B-fragment-order store (coalesced 1KB)
#pragma unroll
  for (int ct = 0; ct < 2; ct++) {
    short8 r8;
#pragma unroll
    for (int i = 0; i < 8; i++) r8[i] = tile[w][ct][q * 8 + i][l];
    size_t chunk = ((size_t)head * (NN / 32) + jb) * 8 + (w * 2 + ct);
    *(short8*)(WhTf + chunk * 512 + lane * 8) = r8;
  }
  // f1/f2 partials from the same tile: thread = (row r, col-group g of 16)
  {
    int r = t & 31, g = t >> 5;
    int ww = g >> 1, cc = g & 1;
    float s1 = 0.f, s2 = 0.f;
#pragma unroll
    for (int li = 0; li < 16; li++) {
      float v = bf2f(tile[ww][cc][r][li]);
      s1 += v * avs[g * 16 + li];
      s2 += v * avs[128 + g * 16 + li];
    }
    fp[0][g][r] = s1; fp[1][g][r] = s2;
  }
  __syncthreads();
  if (t < 32) {
    float s1 = 0.f, s2 = 0.f;
#pragma unroll
    for (int g2 = 0; g2 < 8; g2++) { s1 += fp[0][g2][t]; s2 += fp[1][g2][t]; }
    f1[head * NN + rowbase + t] = s1;
    f2[head * NN + rowbase + t] = s2;
  }
}

// ---- out-layer GEMM, K split across blocks into fp32 partials ----
template<int K, int KS>
__global__ __launch_bounds__(256) void k_gemm_out(const unsigned short* __restrict__ A,
                                                  const unsigned short* __restrict__ WT,
                                                  float* __restrict__ gpart) {
  constexpr int KC = K / KS;
  int ks = blockIdx.y;
  int rowbase = blockIdx.x * 16;
  int t = threadIdx.x;
  int w = t >> 6, lane = t & 63;
  int q = lane >> 4, l = lane & 15;
  int colbase = w * 16;
  float4v acc = {0.f, 0.f, 0.f, 0.f};
  for (int kb = ks * KC; kb < ks * KC + KC; kb += 32) {
    short8 af = *(const short8*)(A + (size_t)(rowbase + l) * K + kb + q * 8);
    short8 bfr = *(const short8*)(WT + (size_t)(colbase + l) * K + kb + q * 8);
    acc = __builtin_amdgcn_mfma_f32_16x16x32_bf16(af, bfr, acc, 0, 0, 0);
  }
#pragma unroll
  for (int reg = 0; reg < 4; reg++) {
    int r = rowbase + q * 4 + reg;
    int n = colbase + l;
    gpart[((size_t)ks * 64 + n) * NN + r] = acc[reg];
  }
}

// ---- combine K-split partials, emit WhoTf in fragment order (DC=64) ----
template<int KS>
__global__ __launch_bounds__(256) void k_gemm_red(const float* __restrict__ gpart,
                                                  unsigned short* __restrict__ WhoTf) {
  int tid = blockIdx.x * 256 + threadIdx.x;
  int r = tid % NN, n = tid / NN;
  float s = 0.f;
#pragma unroll
  for (int ks = 0; ks < KS; ks++) s += gpart[((size_t)ks * 64 + n) * NN + r];
  int jb = r >> 5, q = (r >> 3) & 3, i = r & 7, ct = n >> 4, l = n & 15;
  WhoTf[((size_t)(jb * 4 + ct)) * 512 + (q * 16 + l) * 8 + i] = f2bf(s);
}

// ---- f1/f2 from fragment-order WhTf (out layer only) ----
template<int DC>
__global__ __launch_bounds__(256) void k_f12f(const unsigned short* __restrict__ WhTf,
                                              const void* __restrict__ avec,
                                              const int* __restrict__ flag,
                                              float* __restrict__ f1, float* __restrict__ f2) {
  constexpr int NCT = DC / 16;
  int isbf = *flag;
  int head = blockIdx.y;
  int w = threadIdx.x >> 6, lane = threadIdx.x & 63;
  int q = lane >> 4, l = lane & 15;
  int jbIdx = blockIdx.x * 4 + w;
  size_t abase = (size_t)head * 2 * DC;
  float s1[8], s2[8];
#pragma unroll
  for (int i = 0; i < 8; i++) { s1[i] = 0.f; s2[i] = 0.f; }
#pragma unroll
  for (int ct = 0; ct < NCT; ct++) {
    short8 v = *(const short8*)(WhTf + (((size_t)head * (NN / 32) + jbIdx) * NCT + ct) * 512 + lane * 8);
    float a1v = ldin(avec, abase + ct * 16 + l, isbf);
    float a2v = ldin(avec, abase + DC + ct * 16 + l, isbf);
#pragma unroll
    for (int i = 0; i < 8; i++) {
      float f = bf2f((unsigned short)v[i]);
      s1[i] += f * a1v;
      s2[i] += f * a2v;
    }
  }
#pragma unroll
  for (int d = 1; d < 16; d <<= 1)
#pragma unroll
    for (int i = 0; i < 8; i++) {
      s1[i] += __shfl_xor(s1[i], d, 64);
      s2[i] += __shfl_xor(s2[i], d, 64);
    }
  if (l == 0) {
    int r = jbIdx * 32 + q * 8;
#pragma unroll
    for (int i = 0; i < 8; i++) {
      f1[head * NN + r + i] = s1[i];
      f2[head * NN + r + i] = s2[i];
    }
  }
}

// ---- attention partial: LDS-staged B (double-buffered, 1 barrier/iter,
//      prefetch issued AFTER barrier so it never drains), f2+mask staged
//      per block; full-DCOL waves, ones-MFMA denominator, bf16 frag-order
//      partials, head pinned to XCD via blockIdx.x % NH ----
template<int DCOL, int S>
__global__ __launch_bounds__(256, 4) void k_attn_part(
    const unsigned* __restrict__ maskT,
    const float* __restrict__ f1g, const float* __restrict__ f2g,
    const unsigned short* __restrict__ WhTf,
    unsigned short* __restrict__ pnum, float* __restrict__ pden, int NH) {
  constexpr int NCT = DCOL / 16;
  constexpr int JCH = NN / S;
  constexpr int NIT = JCH / 32;
  constexpr int CH = NCT * 512;            // elems per 32-j B chunk
  constexpr int GR = CH / (256 * 8);       // 16B granules per thread
  __shared__ __align__(16) unsigned short Bs[2][CH];
  __shared__ __align__(16) float f2s[JCH];
  __shared__ unsigned ms[NIT * 128];

  int blk = blockIdx.x;
  int head = blk % NH;
  int rest = blk / NH;
  int js = rest % S;
  int bx = rest / S;
  int t = threadIdx.x;
  int w = t >> 6, lane = t & 63;
  int q = lane >> 4, l = lane & 15;
  int rowbase = bx * 128 + w * 32;
  int rowblk = bx * 128;
  size_t headJB = (size_t)head * (NN / 32);
  int j0 = js * JCH;

  // stage f2 chunk + mask words once per block
  for (int i = t; i < JCH; i += 256) f2s[i] = f2g[head * NN + j0 + i];
  for (int i = t; i < NIT * 128; i += 256)
    ms[i] = maskT[(size_t)((j0 >> 5) + (i >> 7)) * NN + rowblk + (i & 127)];
  float f1c0 = f1g[head * NN + rowbase + l] * 1.44269504f;
  float f1c1 = f1g[head * NN + rowbase + 16 + l] * 1.44269504f;

  short8 ones;
#pragma unroll
  for (int i = 0; i < 8; i++) ones[i] = (short)0x3F80;

  float4v acc[2][NCT];
#pragma unroll
  for (int rt = 0; rt < 2; rt++)
#pragma unroll
    for (int ct = 0; ct < NCT; ct++) { float4v z = {0.f, 0.f, 0.f, 0.f}; acc[rt][ct] = z; }
  float4v accd[2];
  accd[0] = float4v{0.f, 0.f, 0.f, 0.f};
  accd[1] = float4v{0.f, 0.f, 0.f, 0.f};

  // prime: load B chunk j0 into registers
  short8 stg[GR];
  {
    const unsigned short* g0 = WhTf + (headJB + (j0 >> 5)) * (size_t)CH;
#pragma unroll
    for (int g = 0; g < GR; g++) stg[g] = *(const short8*)(g0 + g * 2048 + t * 8);
  }

  int cur = 0;
  for (int it = 0; it < NIT; it++) {
    // commit staged chunk to LDS (vmcnt wait covered by previous compute)
#pragma unroll
    for (int g = 0; g < GR; g++)
      *(short8*)(&Bs[cur][g * 2048 + t * 8]) = stg[g];
    __syncthreads();                       // only LDS writes outstanding: cheap
    // issue next chunk's loads AFTER the barrier (never drained by it)
    int itn = (it + 1 < NIT) ? it + 1 : 0;
    const unsigned short* gn = WhTf + (headJB + (j0 >> 5) + itn) * (size_t)CH;
#pragma unroll
    for (int g = 0; g < GR; g++) stg[g] = *(const short8*)(gn + g * 2048 + t * 8);

    unsigned mwc0 = ms[it * 128 + (w * 32 + l)] >> (q * 8);
    unsigned mwc1 = ms[it * 128 + (w * 32 + 16 + l)] >> (q * 8);
    float4v fac = *(const float4v*)(&f2s[it * 32 + q * 8]);
    float4v fbc = *(const float4v*)(&f2s[it * 32 + q * 8 + 4]);
    short8 bfr[NCT];
#pragma unroll
    for (int ct = 0; ct < NCT; ct++)       // LDS pipe, not L1
      bfr[ct] = *(const short8*)(&Bs[cur][ct * 512 + lane * 8]);

    float p0[8], p1[8];
#pragma unroll
    for (int i = 0; i < 8; i++) {
      float fv = (i < 4) ? fac[i] : fbc[i - 4];
      float t0 = fmaf(fv, 1.44269504f, f1c0);
      t0 = __builtin_amdgcn_fmed3f(t0, 0.2f * t0, 43.f);
      t0 = (mwc0 & (1u << i)) ? t0 : -200.f;
      p0[i] = exp2f(t0);
      float t1 = fmaf(fv, 1.44269504f, f1c1);
      t1 = __builtin_amdgcn_fmed3f(t1, 0.2f * t1, 43.f);
      t1 = (mwc1 & (1u << i)) ? t1 : -200.f;
      p1[i] = exp2f(t1);
    }
    union { __hip_bfloat162 b2[4]; short8 s8; } u0, u1;
#pragma unroll
    for (int k = 0; k < 4; k++) {
      u0.b2[k] = __float22bfloat162_rn({p0[2 * k], p0[2 * k + 1]});
      u1.b2[k] = __float22bfloat162_rn({p1[2 * k], p1[2 * k + 1]});
    }
    accd[0] = __builtin_amdgcn_mfma_f32_16x16x32_bf16(u0.s8, ones, accd[0], 0, 0, 0);
    accd[1] = __builtin_amdgcn_mfma_f32_16x16x32_bf16(u1.s8, ones, accd[1], 0, 0, 0);
#pragma unroll
    for (int ct = 0; ct < NCT; ct++) {
      acc[0][ct] = __builtin_amdgcn_mfma_f32_16x16x32_bf16(u0.s8, bfr[ct], acc[0][ct], 0, 0, 0);
      acc[1][ct] = __builtin_amdgcn_mfma_f32_16x16x32_bf16(u1.s8, bfr[ct], acc[1][ct], 0, 0, 0);
    }
    cur ^= 1;
  }

  size_t slab = (size_t)(js * NH + head);
  if (l == 0) {
#pragma unroll
    for (int rt = 0; rt < 2; rt++)
#pragma unroll
      for (int reg = 0; reg < 4; reg++)
        pden[slab * NN + rowbase + rt * 16 + q * 4 + reg] = accd[rt][reg];
  }
  int trb = rowbase >> 4;
#pragma unroll
  for (int rt = 0; rt < 2; rt++)
#pragma unroll
    for (int ct = 0; ct < NCT; ct++) {
      ushort4v u;
      u.x = f2bf(acc[rt][ct].x); u.y = f2bf(acc[rt][ct].y);
      u.z = f2bf(acc[rt][ct].z); u.w = f2bf(acc[rt][ct].w);
      size_t cidx = ((slab * (NN / 16) + trb + rt) * NCT + ct) * 256 + lane * 4;
      *(ushort4v*)(pnum + cidx) = u;
    }
}

// ---- combine partials (bf16 frag-order): divide, ELU, store layer layout ----
template<int DCOL, int S>
__global__ __launch_bounds__(256) void k_attn_reduce(
    const unsigned short* __restrict__ pnum, const float* __restrict__ pden,
    void* __restrict__ outg, long outHeadOff, int outRowStride, int NH,
    const int* __restrict__ flag, int finalOut) {
  constexpr int NCT = DCOL / 16;
  int tid = blockIdx.x * 256 + threadIdx.x;
  int h = tid / (NN * DCOL);
  int e = tid % (NN * DCOL);
  int tile = e >> 8, r4 = e & 255;
  int ct = tile % NCT, tr = tile / NCT;
  int lane = r4 >> 2, reg = r4 & 3;
  int q = lane >> 4, l = lane & 15;
  int row = tr * 16 + q * 4 + reg;
  int col = ct * 16 + l;
  float sn = 0.f, sd = 0.f;
#pragma unroll
  for (int js = 0; js < S; js++) {
    size_t sl = (size_t)(js * NH + h);
    sn += bf2f(pnum[sl * (size_t)(NN * DCOL) + e]);
    sd += pden[sl * NN + row];
  }
  float v = sd > 0.f ? sn / sd : 0.f;
  v = v > 0.f ? v : expm1f(v);
  size_t idx = (size_t)h * outHeadOff + (size_t)row * outRowStride + col;
  if (finalOut && *flag == 0) ((float*)outg)[idx] = v;
  else ((unsigned short*)outg)[idx] = f2bf(v);
}

extern "C" void kernel_launch(void* const* d_in, const int* in_sizes, int n_in,
                              void* d_out, int out_size, void* d_ws, size_t ws_size,
                              hipStream_t stream) {
  const void* x     = d_in[0];
  const void* adj   = d_in[1];
  const int*  obs   = (const int*)d_in[2];
  // d_in[3] s_mat unused (method='base')
  const void* theta = d_in[4];
  const void* W0    = d_in[5];
  const void* a0    = d_in[6];
  const void* W1    = d_in[7];
  const void* a1    = d_in[8];
  const void* Wo    = d_in[9];
  const void* ao    = d_in[10];

  char* ws = (char*)d_ws;
  size_t off = 0;
  auto alloc = [&](size_t bytes) { void* p = ws + off; off += (bytes + 255) & ~(size_t)255; return p; };
  int*            flag  = (int*)alloc(4);
  unsigned*       maskT = (unsigned*)alloc((size_t)NN * NWORD * 4);
  unsigned short* h_bf  = (unsigned short*)alloc((size_t)NN * 256 * 2);
  unsigned short* WhTf  = (unsigned short*)alloc((size_t)HH * 128 * NN * 2);
  float*          f1    = (float*)alloc((size_t)HH * NN * 4);
  float*          f2    = (float*)alloc((size_t)HH * NN * 4);
  unsigned short* h0    = (unsigned short*)alloc((size_t)HH * NN * 128 * 2);
  unsigned short* hc    = (unsigned short*)alloc((size_t)NN * 1024 * 2);
  unsigned short* W0T   = (unsigned short*)alloc((size_t)HH * 128 * 256 * 2);
  unsigned short* W1T   = (unsigned short*)alloc((size_t)HH * 128 * 128 * 2);
  unsigned short* WoT   = (unsigned short*)alloc((size_t)64 * 1024 * 2);
  unsigned short* WhoTf = (unsigned short*)alloc((size_t)64 * NN * 2);
  float*          fo1   = (float*)alloc((size_t)NN * 4);
  float*          fo2   = (float*)alloc((size_t)NN * 4);
  float*          gpart = (float*)alloc((size_t)4 * 64 * NN * 4);

  size_t fixedEnd = off;
  auto needBytes = [&](int s) {
    size_t slabs = (size_t)((s * HH > 32) ? s * HH : 32);
    return fixedEnd + (size_t)s * HH * NN * 128 * 2 + slabs * NN * 4 + 8192;
  };
  int S = (needBytes(8) <= ws_size) ? 8 : (needBytes(4) <= ws_size) ? 4 : 2;
  unsigned short* pnum = (unsigned short*)alloc((size_t)S * HH * NN * 128 * 2);
  float* pden = (float*)alloc((size_t)((S * HH > 32) ? S * HH : 32) * NN * 4);

  k_detect<<<1, 256, 0, stream>>>((const unsigned*)adj, flag);
  k_mask<<<dim3(12, NN), 256, 0, stream>>>(adj, flag, maskT);
  k_prep<<<NN + 1792, 256, 0, stream>>>(x, obs, theta, W0, W1, Wo, flag,
                                        h_bf, W0T, W1T, WoT);

  // ---- layer 0 ----
  k_gemm_fused<256><<<dim3(NN / 32, HH), 256, 0, stream>>>(h_bf, W0T, WhTf,
                                                           0, 128 * 256, a0, flag, f1, f2);
  switch (S) {
    case 8:
      k_attn_part<128, 8><<<(NN / 128) * 8 * HH, 256, 0, stream>>>(maskT, f1, f2, WhTf, pnum, pden, HH);
      k_attn_reduce<128, 8><<<HH * NN * 128 / 256, 256, 0, stream>>>(pnum, pden, h0, (long)NN * 128, 128, HH, flag, 0);
      break;
    case 4:
      k_attn_part<128, 4><<<(NN / 128) * 4 * HH, 256, 0, stream>>>(maskT, f1, f2, WhTf, pnum, pden, HH);
      k_attn_reduce<128, 4><<<HH * NN * 128 / 256, 256, 0, stream>>>(pnum, pden, h0, (long)NN * 128, 128, HH, flag, 0);
      break;
    default:
      k_attn_part<128, 2><<<(NN / 128) * 2 * HH, 256, 0, stream>>>(maskT, f1, f2, WhTf, pnum, pden, HH);
      k_attn_reduce<128, 2><<<HH * NN * 128 / 256, 256, 0, stream>>>(pnum, pden, h0, (long)NN * 128, 128, HH, flag, 0);
  }
  // ---- layer 1 ----
  k_gemm_fused<128><<<dim3(NN / 32, HH), 256, 0, stream>>>(h0, W1T, WhTf,
                                                           (long)NN * 128, 128 * 128, a1, flag, f1, f2);
  switch (S) {
    case 8:
      k_attn_part<128, 8><<<(NN / 128) * 8 * HH, 256, 0, stream>>>(maskT, f1, f2, WhTf, pnum, pden, HH);
      k_attn_reduce<128, 8><<<HH * NN * 128 / 256, 256, 0, stream>>>(pnum, pden, hc, 128, 1024, HH, flag, 0);
      break;
    case 4:
      k_attn_part<128, 4><<<(NN / 128) * 4 * HH, 256, 0, stream>>>(maskT, f1, f2, WhTf, pnum, pden, HH);
      k_attn_reduce<128, 4><<<HH * NN * 128 / 256, 256, 0, stream>>>(pnum, pden, hc, 128, 1024, HH, flag, 0);
      break;
    default:
      k_attn_part<128, 2><<<(NN / 128) * 2 * HH, 256, 0, stream>>>(maskT, f1, f2, WhTf, pnum, pden, HH);
      k_attn_reduce<128, 2><<<HH * NN * 128 / 256, 256, 0, stream>>>(pnum, pden, hc, 128, 1024, HH, flag, 0);
  }
  // ---- output layer ----
  k_gemm_out<1024, 4><<<dim3(NN / 16, 4), 256, 0, stream>>>(hc, WoT, gpart);
  k_gemm_red<4><<<64 * NN / 256, 256, 0, stream>>>(gpart, WhoTf);
  k_f12f<64><<<dim3(NN / 128, 1), 256, 0, stream>>>(WhoTf, ao, flag, fo1, fo2);
  k_attn_part<64, 32><<<(NN / 128) * 32, 256, 0, stream>>>(maskT, fo1, fo2, WhoTf, pnum, pden, 1);
  k_attn_reduce<64, 32><<<NN * 64 / 256, 256, 0, stream>>>(pnum, pden, d_out, 0, 64, 1, flag, 1);
}

// Round 14
// 300.089 us; speedup vs baseline: 1.3067x; 1.0239x over previous
//
#include <hip/hip_runtime.h>
#include <hip/hip_bf16.h>

#define NN 3072
#define NWORD 96
#define HH 8

typedef short short8 __attribute__((ext_vector_type(8)));
typedef float float4v __attribute__((ext_vector_type(4)));
typedef unsigned short ushort4v __attribute__((ext_vector_type(4)));

__device__ __forceinline__ float bf2f(unsigned short u) {
  union { unsigned u; float f; } v; v.u = ((unsigned)u) << 16; return v.f;
}
__device__ __forceinline__ unsigned short f2bf(float f) {
  union { float f; unsigned u; } v; v.f = f;
  unsigned r = v.u + 0x7fffu + ((v.u >> 16) & 1u);
  return (unsigned short)(r >> 16);
}
// flag==1 -> buffers are bf16; flag==0 -> fp32
__device__ __forceinline__ float ldin(const void* p, size_t i, int isbf) {
  return isbf ? bf2f(((const unsigned short*)p)[i]) : ((const float*)p)[i];
}

// ---- dtype detect ----
__global__ __launch_bounds__(256) void k_detect(const unsigned* __restrict__ aw,
                                                int* __restrict__ flag) {
  __shared__ int s;
  if (threadIdx.x == 0) s = 0;
  __syncthreads();
  int any = 0;
  for (int i = threadIdx.x; i < 16384; i += 256)
    any |= ((aw[i] & 0xFFFFu) != 0u);
  if (any) s = 1;   // benign race
  __syncthreads();
  if (threadIdx.x == 0) *flag = s;
}

// ---- build TRANSPOSED bitmask: maskT[word][row] (1.2 MB, L2-resident) ----
__global__ __launch_bounds__(256) void k_mask(const void* __restrict__ adj,
                                              const int* __restrict__ flag,
                                              unsigned* __restrict__ maskT) {
  int isbf = *flag;
  int row = blockIdx.y;
  int j = blockIdx.x * 256 + threadIdx.x;
  bool pred = ldin(adj, (size_t)row * NN + j, isbf) != 0.f;
  unsigned long long b = __ballot(pred);
  int lane = threadIdx.x & 63;
  int word = blockIdx.x * 8 + (threadIdx.x >> 6) * 2;
  if (lane == 0) maskT[(size_t)word * NN + row] = (unsigned)b;
  else if (lane == 32) maskT[(size_t)(word + 1) * NN + row] = (unsigned)(b >> 32);
}

// ---- prep: mergeState (blocks 0..NN) + all three weight transposes ----
__global__ __launch_bounds__(256) void k_prep(const void* __restrict__ x,
                                              const int* __restrict__ obs,
                                              const void* __restrict__ theta,
                                              const void* __restrict__ W0,
                                              const void* __restrict__ W1,
                                              const void* __restrict__ Wo,
                                              const int* __restrict__ flag,
                                              unsigned short* __restrict__ h_bf,
                                              unsigned short* __restrict__ W0T,
                                              unsigned short* __restrict__ W1T,
                                              unsigned short* __restrict__ WoT) {
  __shared__ __align__(16) unsigned short tile[16][17];
  int isbf = *flag;
  int t = threadIdx.x;
  int b = blockIdx.x;
  if (b < NN) {                          // mergeState
    int i = b * 256 + t;
    int row = i >> 8, c = i & 255;
    float v = ldin(x, i, isbf);
    if (obs[row] == 1) v += ldin(theta, c, isbf);
    h_bf[i] = f2bf(v);
    return;
  }
  b -= NN;
  const void* in; unsigned short* out; int R, C, r0, c0;
  if (b < 1024) {                        // W0: 8 heads x (16 x 8) tiles, 256x128
    int h = b >> 7, rem = b & 127;
    in = (const char*)W0 + (size_t)h * 256 * 128 * (isbf ? 2 : 4);
    out = W0T + (size_t)h * 256 * 128;
    R = 256; C = 128; r0 = (rem >> 3) * 16; c0 = (rem & 7) * 16;
  } else if (b < 1536) {                 // W1: 8 heads x (8 x 8), 128x128
    b -= 1024;
    int h = b >> 6, rem = b & 63;
    in = (const char*)W1 + (size_t)h * 128 * 128 * (isbf ? 2 : 4);
    out = W1T + (size_t)h * 128 * 128;
    R = 128; C = 128; r0 = (rem >> 3) * 16; c0 = (rem & 7) * 16;
  } else {                               // Wo: (64 x 4), 1024x64
    b -= 1536;
    in = Wo; out = WoT;
    R = 1024; C = 64; r0 = (b >> 2) * 16; c0 = (b & 3) * 16;
  }
  int tc = t & 15, tr = t >> 4;
  tile[tr][tc] = f2bf(ldin(in, (size_t)(r0 + tr) * C + (c0 + tc), isbf));
  __syncthreads();
  out[(size_t)(c0 + tr) * R + (r0 + tc)] = tile[tc][tr];
}

// ---- fused GEMM: 32 rows x 128 cols/block; head = blk % HH pins each head's
//      WhTf/f1/f2 writes to the XCD that consumes them in attention ----
template<int K>
__global__ __launch_bounds__(256) void k_gemm_fused(const unsigned short* __restrict__ A,
                                                    const unsigned short* __restrict__ WT,
                                                    unsigned short* __restrict__ WhTf,
                                                    long aOff, long wOff,
                                                    const void* __restrict__ avec,
                                                    const int* __restrict__ flag,
                                                    float* __restrict__ f1,
                                                    float* __restrict__ f2) {
  __shared__ __align__(16) unsigned short tile[4][2][32][17];
  __shared__ float avs[256];
  __shared__ float fp[2][8][32];
  int isbf = *flag;
  int head = blockIdx.x % HH;            // XCD pin
  int jb = blockIdx.x / HH;
  A += (size_t)head * aOff; WT += (size_t)head * wOff;
  int rowbase = jb * 32;
  int t = threadIdx.x;
  int w = t >> 6, lane = t & 63;
  int q = lane >> 4, l = lane & 15;
  int colbase = w * 32;
  avs[t] = ldin(avec, (size_t)head * 256 + t, isbf);
  float4v acc[2][2];
#pragma unroll
  for (int rt = 0; rt < 2; rt++)
#pragma unroll
    for (int ct = 0; ct < 2; ct++) { float4v z = {0.f, 0.f, 0.f, 0.f}; acc[rt][ct] = z; }

  for (int kb = 0; kb < K; kb += 32) {
    short8 af[2], bfr[2];
#pragma unroll
    for (int rt = 0; rt < 2; rt++)
      af[rt] = *(const short8*)(A + (size_t)(rowbase + rt * 16 + l) * K + kb + q * 8);
#pragma unroll
    for (int ct = 0; ct < 2; ct++)
      bfr[ct] = *(const short8*)(WT + (size_t)(colbase + ct * 16 + l) * K + kb + q * 8);
#pragma unroll
    for (int rt = 0; rt < 2; rt++)
#pragma unroll
      for (int ct = 0; ct < 2; ct++)
        acc[rt][ct] = __builtin_amdgcn_mfma_f32_16x16x32_bf16(af[rt], bfr[ct], acc[rt][ct], 0, 0, 0);
  }
#pragma unroll
  for (int rt = 0; rt < 2; rt++)
#pragma unroll
    for (int ct = 0; ct < 2; ct++)
#pragma unroll
      for (int reg = 0; reg < 4; reg++)
        tile[w][ct][rt * 16 + q * 4 + reg][l] = f2bf(acc[rt][ct][reg]);
  __syncthreads();
  // B-fragment-order store (coalesced 1KB)
#pragma unroll
  for (int ct = 0; ct < 2; ct++) {
    short8 r8;
#pragma unroll
    for (int i = 0; i < 8; i++) r8[i] = tile[w][ct][q * 8 + i][l];
    size_t chunk = ((size_t)head * (NN / 32) + jb) * 8 + (w * 2 + ct);
    *(short8*)(WhTf + chunk * 512 + lane * 8) = r8;
  }
  // f1/f2 partials from the same tile
  {
    int r = t & 31, g = t >> 5;
    int ww = g >> 1, cc = g & 1;
    float s1 = 0.f, s2 = 0.f;
#pragma unroll
    for (int li = 0; li < 16; li++) {
      float v = bf2f(tile[ww][cc][r][li]);
      s1 += v * avs[g * 16 + li];
      s2 += v * avs[128 + g * 16 + li];
    }
    fp[0][g][r] = s1; fp[1][g][r] = s2;
  }
  __syncthreads();
  if (t < 32) {
    float s1 = 0.f, s2 = 0.f;
#pragma unroll
    for (int g2 = 0; g2 < 8; g2++) { s1 += fp[0][g2][t]; s2 += fp[1][g2][t]; }
    f1[head * NN + rowbase + t] = s1;
    f2[head * NN + rowbase + t] = s2;
  }
}

// ---- out-layer GEMM, K split across blocks into fp32 partials ----
template<int K, int KS>
__global__ __launch_bounds__(256) void k_gemm_out(const unsigned short* __restrict__ A,
                                                  const unsigned short* __restrict__ WT,
                                                  float* __restrict__ gpart) {
  constexpr int KC = K / KS;
  int ks = blockIdx.y;
  int rowbase = blockIdx.x * 16;
  int t = threadIdx.x;
  int w = t >> 6, lane = t & 63;
  int q = lane >> 4, l = lane & 15;
  int colbase = w * 16;
  float4v acc = {0.f, 0.f, 0.f, 0.f};
  for (int kb = ks * KC; kb < ks * KC + KC; kb += 32) {
    short8 af = *(const short8*)(A + (size_t)(rowbase + l) * K + kb + q * 8);
    short8 bfr = *(const short8*)(WT + (size_t)(colbase + l) * K + kb + q * 8);
    acc = __builtin_amdgcn_mfma_f32_16x16x32_bf16(af, bfr, acc, 0, 0, 0);
  }
#pragma unroll
  for (int reg = 0; reg < 4; reg++) {
    int r = rowbase + q * 4 + reg;
    int n = colbase + l;
    gpart[((size_t)ks * 64 + n) * NN + r] = acc[reg];
  }
}

// ---- combine K-split partials, emit WhoTf in fragment order (DC=64) ----
template<int KS>
__global__ __launch_bounds__(256) void k_gemm_red(const float* __restrict__ gpart,
                                                  unsigned short* __restrict__ WhoTf) {
  int tid = blockIdx.x * 256 + threadIdx.x;
  int r = tid % NN, n = tid / NN;
  float s = 0.f;
#pragma unroll
  for (int ks = 0; ks < KS; ks++) s += gpart[((size_t)ks * 64 + n) * NN + r];
  int jb = r >> 5, q = (r >> 3) & 3, i = r & 7, ct = n >> 4, l = n & 15;
  WhoTf[((size_t)(jb * 4 + ct)) * 512 + (q * 16 + l) * 8 + i] = f2bf(s);
}

// ---- f1/f2 from fragment-order WhTf (out layer only) ----
template<int DC>
__global__ __launch_bounds__(256) void k_f12f(const unsigned short* __restrict__ WhTf,
                                              const void* __restrict__ avec,
                                              const int* __restrict__ flag,
                                              float* __restrict__ f1, float* __restrict__ f2) {
  constexpr int NCT = DC / 16;
  int isbf = *flag;
  int head = blockIdx.y;
  int w = threadIdx.x >> 6, lane = threadIdx.x & 63;
  int q = lane >> 4, l = lane & 15;
  int jbIdx = blockIdx.x * 4 + w;
  size_t abase = (size_t)head * 2 * DC;
  float s1[8], s2[8];
#pragma unroll
  for (int i = 0; i < 8; i++) { s1[i] = 0.f; s2[i] = 0.f; }
#pragma unroll
  for (int ct = 0; ct < NCT; ct++) {
    short8 v = *(const short8*)(WhTf + (((size_t)head * (NN / 32) + jbIdx) * NCT + ct) * 512 + lane * 8);
    float a1v = ldin(avec, abase + ct * 16 + l, isbf);
    float a2v = ldin(avec, abase + DC + ct * 16 + l, isbf);
#pragma unroll
    for (int i = 0; i < 8; i++) {
      float f = bf2f((unsigned short)v[i]);
      s1[i] += f * a1v;
      s2[i] += f * a2v;
    }
  }
#pragma unroll
  for (int d = 1; d < 16; d <<= 1)
#pragma unroll
    for (int i = 0; i < 8; i++) {
      s1[i] += __shfl_xor(s1[i], d, 64);
      s2[i] += __shfl_xor(s2[i], d, 64);
    }
  if (l == 0) {
    int r = jbIdx * 32 + q * 8;
#pragma unroll
    for (int i = 0; i < 8; i++) {
      f1[head * NN + r + i] = s1[i];
      f2[head * NN + r + i] = s2[i];
    }
  }
}

// ---- attention partial: LDS-staged B (double-buffered, post-barrier
//      prefetch), f2+mask staged per block; ones-MFMA denominator,
//      bf16 frag-order partials, head pinned to XCD via blockIdx.x % NH ----
template<int DCOL, int S>
__global__ __launch_bounds__(256, 4) void k_attn_part(
    const unsigned* __restrict__ maskT,
    const float* __restrict__ f1g, const float* __restrict__ f2g,
    const unsigned short* __restrict__ WhTf,
    unsigned short* __restrict__ pnum, float* __restrict__ pden, int NH) {
  constexpr int NCT = DCOL / 16;
  constexpr int JCH = NN / S;
  constexpr int NIT = JCH / 32;
  constexpr int CH = NCT * 512;
  constexpr int GR = CH / (256 * 8);
  __shared__ __align__(16) unsigned short Bs[2][CH];
  __shared__ __align__(16) float f2s[JCH];
  __shared__ unsigned ms[NIT * 128];

  int blk = blockIdx.x;
  int head = blk % NH;
  int rest = blk / NH;
  int js = rest % S;
  int bx = rest / S;
  int t = threadIdx.x;
  int w = t >> 6, lane = t & 63;
  int q = lane >> 4, l = lane & 15;
  int rowbase = bx * 128 + w * 32;
  int rowblk = bx * 128;
  size_t headJB = (size_t)head * (NN / 32);
  int j0 = js * JCH;

  for (int i = t; i < JCH; i += 256) f2s[i] = f2g[head * NN + j0 + i];
  for (int i = t; i < NIT * 128; i += 256)
    ms[i] = maskT[(size_t)((j0 >> 5) + (i >> 7)) * NN + rowblk + (i & 127)];
  float f1c0 = f1g[head * NN + rowbase + l] * 1.44269504f;
  float f1c1 = f1g[head * NN + rowbase + 16 + l] * 1.44269504f;

  short8 ones;
#pragma unroll
  for (int i = 0; i < 8; i++) ones[i] = (short)0x3F80;

  float4v acc[2][NCT];
#pragma unroll
  for (int rt = 0; rt < 2; rt++)
#pragma unroll
    for (int ct = 0; ct < NCT; ct++) { float4v z = {0.f, 0.f, 0.f, 0.f}; acc[rt][ct] = z; }
  float4v accd[2];
  accd[0] = float4v{0.f, 0.f, 0.f, 0.f};
  accd[1] = float4v{0.f, 0.f, 0.f, 0.f};

  short8 stg[GR];
  {
    const unsigned short* g0 = WhTf + (headJB + (j0 >> 5)) * (size_t)CH;
#pragma unroll
    for (int g = 0; g < GR; g++) stg[g] = *(const short8*)(g0 + g * 2048 + t * 8);
  }

  int cur = 0;
  for (int it = 0; it < NIT; it++) {
#pragma unroll
    for (int g = 0; g < GR; g++)
      *(short8*)(&Bs[cur][g * 2048 + t * 8]) = stg[g];
    __syncthreads();
    int itn = (it + 1 < NIT) ? it + 1 : 0;
    const unsigned short* gn = WhTf + (headJB + (j0 >> 5) + itn) * (size_t)CH;
#pragma unroll
    for (int g = 0; g < GR; g++) stg[g] = *(const short8*)(gn + g * 2048 + t * 8);

    unsigned mwc0 = ms[it * 128 + (w * 32 + l)] >> (q * 8);
    unsigned mwc1 = ms[it * 128 + (w * 32 + 16 + l)] >> (q * 8);
    float4v fac = *(const float4v*)(&f2s[it * 32 + q * 8]);
    float4v fbc = *(const float4v*)(&f2s[it * 32 + q * 8 + 4]);
    short8 bfr[NCT];
#pragma unroll
    for (int ct = 0; ct < NCT; ct++)
      bfr[ct] = *(const short8*)(&Bs[cur][ct * 512 + lane * 8]);

    float p0[8], p1[8];
#pragma unroll
    for (int i = 0; i < 8; i++) {
      float fv = (i < 4) ? fac[i] : fbc[i - 4];
      float t0 = fmaf(fv, 1.44269504f, f1c0);
      t0 = __builtin_amdgcn_fmed3f(t0, 0.2f * t0, 43.f);
      t0 = (mwc0 & (1u << i)) ? t0 : -200.f;
      p0[i] = exp2f(t0);
      float t1 = fmaf(fv, 1.44269504f, f1c1);
      t1 = __builtin_amdgcn_fmed3f(t1, 0.2f * t1, 43.f);
      t1 = (mwc1 & (1u << i)) ? t1 : -200.f;
      p1[i] = exp2f(t1);
    }
    union { __hip_bfloat162 b2[4]; short8 s8; } u0, u1;
#pragma unroll
    for (int k = 0; k < 4; k++) {
      u0.b2[k] = __float22bfloat162_rn({p0[2 * k], p0[2 * k + 1]});
      u1.b2[k] = __float22bfloat162_rn({p1[2 * k], p1[2 * k + 1]});
    }
    accd[0] = __builtin_amdgcn_mfma_f32_16x16x32_bf16(u0.s8, ones, accd[0], 0, 0, 0);
    accd[1] = __builtin_amdgcn_mfma_f32_16x16x32_bf16(u1.s8, ones, accd[1], 0, 0, 0);
#pragma unroll
    for (int ct = 0; ct < NCT; ct++) {
      acc[0][ct] = __builtin_amdgcn_mfma_f32_16x16x32_bf16(u0.s8, bfr[ct], acc[0][ct], 0, 0, 0);
      acc[1][ct] = __builtin_amdgcn_mfma_f32_16x16x32_bf16(u1.s8, bfr[ct], acc[1][ct], 0, 0, 0);
    }
    cur ^= 1;
  }

  size_t slab = (size_t)(js * NH + head);
  if (l == 0) {
#pragma unroll
    for (int rt = 0; rt < 2; rt++)
#pragma unroll
      for (int reg = 0; reg < 4; reg++)
        pden[slab * NN + rowbase + rt * 16 + q * 4 + reg] = accd[rt][reg];
  }
  int trb = rowbase >> 4;
#pragma unroll
  for (int rt = 0; rt < 2; rt++)
#pragma unroll
    for (int ct = 0; ct < NCT; ct++) {
      ushort4v u;
      u.x = f2bf(acc[rt][ct].x); u.y = f2bf(acc[rt][ct].y);
      u.z = f2bf(acc[rt][ct].z); u.w = f2bf(acc[rt][ct].w);
      size_t cidx = ((slab * (NN / 16) + trb + rt) * NCT + ct) * 256 + lane * 4;
      *(ushort4v*)(pnum + cidx) = u;
    }
}

// ---- combine partials: 4 elems/thread (vector loads), head-pinned so pnum
//      reads hit the L2 of the XCD that wrote them ----
template<int DCOL, int S>
__global__ __launch_bounds__(256) void k_attn_reduce(
    const unsigned short* __restrict__ pnum, const float* __restrict__ pden,
    void* __restrict__ outg, long outHeadOff, int outRowStride, int NH,
    const int* __restrict__ flag, int finalOut) {
  constexpr int NCT = DCOL / 16;
  int blk = blockIdx.x;
  int h = blk % NH;                        // XCD pin, matches attn writer
  int bi = blk / NH;
  int t = threadIdx.x;
  int base = bi * 1024 + t * 4;            // e-base within head's NN*DCOL slab
  int tile = base >> 8;
  int lane = (base >> 2) & 63;
  int ct = tile % NCT, tr = tile / NCT;
  int q = lane >> 4, l = lane & 15;
  int row0 = tr * 16 + q * 4;
  int col = ct * 16 + l;
  float sn[4] = {0.f, 0.f, 0.f, 0.f};
  float sd[4] = {0.f, 0.f, 0.f, 0.f};
#pragma unroll
  for (int js = 0; js < S; js++) {
    size_t sl = (size_t)(js * NH + h);
    ushort4v pv = *(const ushort4v*)(pnum + sl * (size_t)(NN * DCOL) + base);
    float4v dv = *(const float4v*)(pden + sl * NN + row0);
    sn[0] += bf2f(pv.x); sn[1] += bf2f(pv.y); sn[2] += bf2f(pv.z); sn[3] += bf2f(pv.w);
    sd[0] += dv.x; sd[1] += dv.y; sd[2] += dv.z; sd[3] += dv.w;
  }
  int f32o = finalOut && (*flag == 0);
#pragma unroll
  for (int r = 0; r < 4; r++) {
    float v = sd[r] > 0.f ? sn[r] / sd[r] : 0.f;
    v = v > 0.f ? v : expm1f(v);           // ELU
    size_t idx = (size_t)h * outHeadOff + (size_t)(row0 + r) * outRowStride + col;
    if (f32o) ((float*)outg)[idx] = v;
    else ((unsigned short*)outg)[idx] = f2bf(v);
  }
}

extern "C" void kernel_launch(void* const* d_in, const int* in_sizes, int n_in,
                              void* d_out, int out_size, void* d_ws, size_t ws_size,
                              hipStream_t stream) {
  const void* x     = d_in[0];
  const void* adj   = d_in[1];
  const int*  obs   = (const int*)d_in[2];
  // d_in[3] s_mat unused (method='base')
  const void* theta = d_in[4];
  const void* W0    = d_in[5];
  const void* a0    = d_in[6];
  const void* W1    = d_in[7];
  const void* a1    = d_in[8];
  const void* Wo    = d_in[9];
  const void* ao    = d_in[10];

  char* ws = (char*)d_ws;
  size_t off = 0;
  auto alloc = [&](size_t bytes) { void* p = ws + off; off += (bytes + 255) & ~(size_t)255; return p; };
  int*            flag  = (int*)alloc(4);
  unsigned*       maskT = (unsigned*)alloc((size_t)NN * NWORD * 4);
  unsigned short* h_bf  = (unsigned short*)alloc((size_t)NN * 256 * 2);
  unsigned short* WhTf  = (unsigned short*)alloc((size_t)HH * 128 * NN * 2);
  float*          f1    = (float*)alloc((size_t)HH * NN * 4);
  float*          f2    = (float*)alloc((size_t)HH * NN * 4);
  unsigned short* h0    = (unsigned short*)alloc((size_t)HH * NN * 128 * 2);
  unsigned short* hc    = (unsigned short*)alloc((size_t)NN * 1024 * 2);
  unsigned short* W0T   = (unsigned short*)alloc((size_t)HH * 128 * 256 * 2);
  unsigned short* W1T   = (unsigned short*)alloc((size_t)HH * 128 * 128 * 2);
  unsigned short* WoT   = (unsigned short*)alloc((size_t)64 * 1024 * 2);
  unsigned short* WhoTf = (unsigned short*)alloc((size_t)64 * NN * 2);
  float*          fo1   = (float*)alloc((size_t)NN * 4);
  float*          fo2   = (float*)alloc((size_t)NN * 4);
  float*          gpart = (float*)alloc((size_t)4 * 64 * NN * 4);

  size_t fixedEnd = off;
  auto needBytes = [&](int s) {
    size_t slabs = (size_t)((s * HH > 32) ? s * HH : 32);
    return fixedEnd + (size_t)s * HH * NN * 128 * 2 + slabs * NN * 4 + 8192;
  };
  int S = (needBytes(8) <= ws_size) ? 8 : (needBytes(4) <= ws_size) ? 4 : 2;
  unsigned short* pnum = (unsigned short*)alloc((size_t)S * HH * NN * 128 * 2);
  float* pden = (float*)alloc((size_t)((S * HH > 32) ? S * HH : 32) * NN * 4);

  k_detect<<<1, 256, 0, stream>>>((const unsigned*)adj, flag);
  k_mask<<<dim3(12, NN), 256, 0, stream>>>(adj, flag, maskT);
  k_prep<<<NN + 1792, 256, 0, stream>>>(x, obs, theta, W0, W1, Wo, flag,
                                        h_bf, W0T, W1T, WoT);

  // ---- layer 0 ----
  k_gemm_fused<256><<<(NN / 32) * HH, 256, 0, stream>>>(h_bf, W0T, WhTf,
                                                        0, 128 * 256, a0, flag, f1, f2);
  switch (S) {
    case 8:
      k_attn_part<128, 8><<<(NN / 128) * 8 * HH, 256, 0, stream>>>(maskT, f1, f2, WhTf, pnum, pden, HH);
      k_attn_reduce<128, 8><<<HH * NN * 128 / 1024, 256, 0, stream>>>(pnum, pden, h0, (long)NN * 128, 128, HH, flag, 0);
      break;
    case 4:
      k_attn_part<128, 4><<<(NN / 128) * 4 * HH, 256, 0, stream>>>(maskT, f1, f2, WhTf, pnum, pden, HH);
      k_attn_reduce<128, 4><<<HH * NN * 128 / 1024, 256, 0, stream>>>(pnum, pden, h0, (long)NN * 128, 128, HH, flag, 0);
      break;
    default:
      k_attn_part<128, 2><<<(NN / 128) * 2 * HH, 256, 0, stream>>>(maskT, f1, f2, WhTf, pnum, pden, HH);
      k_attn_reduce<128, 2><<<HH * NN * 128 / 1024, 256, 0, stream>>>(pnum, pden, h0, (long)NN * 128, 128, HH, flag, 0);
  }
  // ---- layer 1 ----
  k_gemm_fused<128><<<(NN / 32) * HH, 256, 0, stream>>>(h0, W1T, WhTf,
                                                        (long)NN * 128, 128 * 128, a1, flag, f1, f2);
  switch (S) {
    case 8:
      k_attn_part<128, 8><<<(NN / 128) * 8 * HH, 256, 0, stream>>>(maskT, f1, f2, WhTf, pnum, pden, HH);
      k_attn_reduce<128, 8><<<HH * NN * 128 / 1024, 256, 0, stream>>>(pnum, pden, hc, 128, 1024, HH, flag, 0);
      break;
    case 4:
      k_attn_part<128, 4><<<(NN / 128) * 4 * HH, 256, 0, stream>>>(maskT, f1, f2, WhTf, pnum, pden, HH);
      k_attn_reduce<128, 4><<<HH * NN * 128 / 1024, 256, 0, stream>>>(pnum, pden, hc, 128, 1024, HH, flag, 0);
      break;
    default:
      k_attn_part<128, 2><<<(NN / 128) * 2 * HH, 256, 0, stream>>>(maskT, f1, f2, WhTf, pnum, pden, HH);
      k_attn_reduce<128, 2><<<HH * NN * 128 / 1024, 256, 0, stream>>>(pnum, pden, hc, 128, 1024, HH, flag, 0);
  }
  // ---- output layer ----
  k_gemm_out<1024, 4><<<dim3(NN / 16, 4), 256, 0, stream>>>(hc, WoT, gpart);
  k_gemm_red<4><<<64 * NN / 256, 256, 0, stream>>>(gpart, WhoTf);
  k_f12f<64><<<dim3(NN / 128, 1), 256, 0, stream>>>(WhoTf, ao, flag, fo1, fo2);
  k_attn_part<64, 32><<<(NN / 128) * 32, 256, 0, stream>>>(maskT, fo1, fo2, WhoTf, pnum, pden, 1);
  k_attn_reduce<64, 32><<<NN * 64 / 1024, 256, 0, stream>>>(pnum, pden, d_out, 0, 64, 1, flag, 1);
}